// Round 1
// baseline (3244.336 us; speedup 1.0000x reference)
//
#include <hip/hip_runtime.h>

#define BB 4
#define NN 4096
#define DIMM 512
#define HH 8
#define DH 64
#define GSZ 128
#define NGRP 32
#define WSZ 256
#define CHUNK 32

// ---------------------------------------------------------------------------
// GEMM: C = A(16384x512) @ W(512x512); blockIdx.z selects among 3 W/C pairs.
// 128x128 tile, BK=32, 8x8 microtile per thread, 256 threads.
// ---------------------------------------------------------------------------
__global__ __launch_bounds__(256) void gemm512(
    const float* __restrict__ A,
    const float* __restrict__ W0, const float* __restrict__ W1, const float* __restrict__ W2,
    float* __restrict__ C0, float* __restrict__ C1, float* __restrict__ C2)
{
  const int z = blockIdx.z;
  const float* Wm = (z == 0) ? W0 : (z == 1 ? W1 : W2);
  float* Cm = (z == 0) ? C0 : (z == 1 ? C1 : C2);
  const int n0 = blockIdx.x * 128;
  const int m0 = blockIdx.y * 128;
  const int tid = threadIdx.x;
  const int tx = tid & 15, ty = tid >> 4;

  __shared__ float As[32][132];   // transposed A tile: As[k][m]
  __shared__ float Bs[32][132];   // Bs[k][n]

  float acc[8][8];
#pragma unroll
  for (int i = 0; i < 8; ++i)
#pragma unroll
    for (int j = 0; j < 8; ++j) acc[i][j] = 0.f;

  for (int k0 = 0; k0 < 512; k0 += 32) {
    {
      const int c4 = tid & 7, r = tid >> 3;
#pragma unroll
      for (int p = 0; p < 128; p += 32) {
        float4 av = *(const float4*)&A[(size_t)(m0 + r + p) * 512 + k0 + c4 * 4];
        As[c4 * 4 + 0][r + p] = av.x;
        As[c4 * 4 + 1][r + p] = av.y;
        As[c4 * 4 + 2][r + p] = av.z;
        As[c4 * 4 + 3][r + p] = av.w;
      }
      const int j4 = tid & 31, rb = tid >> 5;
#pragma unroll
      for (int p = 0; p < 32; p += 8) {
        *(float4*)&Bs[rb + p][j4 * 4] =
            *(const float4*)&Wm[(size_t)(k0 + rb + p) * 512 + n0 + j4 * 4];
      }
    }
    __syncthreads();
#pragma unroll
    for (int kk = 0; kk < 32; ++kk) {
      float4 a0 = *(const float4*)&As[kk][ty * 8];
      float4 a1 = *(const float4*)&As[kk][ty * 8 + 4];
      float4 b0 = *(const float4*)&Bs[kk][tx * 8];
      float4 b1 = *(const float4*)&Bs[kk][tx * 8 + 4];
      float av[8] = {a0.x, a0.y, a0.z, a0.w, a1.x, a1.y, a1.z, a1.w};
      float bv[8] = {b0.x, b0.y, b0.z, b0.w, b1.x, b1.y, b1.z, b1.w};
#pragma unroll
      for (int i = 0; i < 8; ++i)
#pragma unroll
        for (int j = 0; j < 8; ++j) acc[i][j] += av[i] * bv[j];
    }
    __syncthreads();
  }
#pragma unroll
  for (int i = 0; i < 8; ++i) {
    size_t row = (size_t)(m0 + ty * 8 + i);
    float4 o0 = make_float4(acc[i][0], acc[i][1], acc[i][2], acc[i][3]);
    float4 o1 = make_float4(acc[i][4], acc[i][5], acc[i][6], acc[i][7]);
    *(float4*)&Cm[row * 512 + n0 + tx * 8] = o0;
    *(float4*)&Cm[row * 512 + n0 + tx * 8 + 4] = o1;
  }
}

// ---------------------------------------------------------------------------
// Fused sparse attention. One block per (b, g, h). 256 threads (4 waves).
// Processes 128 q-rows in 4 chunks of 32. o aliases the q buffer (safe:
// each block reads exactly the q slice it later overwrites, read-first).
// ---------------------------------------------------------------------------
__global__ __launch_bounds__(256) void attn_kernel(
    const float* q,                    // aliases o
    const float* __restrict__ k,
    const float* __restrict__ v,
    const int* __restrict__ labels,
    const float* __restrict__ scores,
    float* __restrict__ attn_out,
    float* o)                          // aliases q
{
  const int blk = blockIdx.x;
  const int h = blk % HH;
  const int g = (blk / HH) % NGRP;
  const int b = blk / (HH * NGRP);
  const int tid = threadIdx.x;
  const int lane = tid & 63, wv = tid >> 6;

  __shared__ float att[CHUNK][WSZ + 4];    // 32 x 260 : logits -> a -> p
  __shared__ float qbuf[CHUNK][DH + 4];    // 32 x 68
  __shared__ float ktile[64][DH + 4];      // 64 x 68 (k, then v)
  __shared__ int klab[WSZ];
  __shared__ float kscr[WSZ];
  __shared__ int qlab[GSZ];
  __shared__ float qscr[GSZ];
  __shared__ int hist8[8];
  __shared__ int s_sk, s_ck;

  // ---- labels / scores (window map: pos>=N -> 2N-1-pos, the flipped tail) ----
  if (tid < GSZ) {
    int t0 = b * NN + g * GSZ + tid;
    qlab[tid] = labels[t0];
    qscr[tid] = scores[t0];
  }
  {
    int j = tid;  // 256 threads == WSZ
    int pos = g * GSZ + j;
    int tok = pos < NN ? pos : (2 * NN - 1 - pos);
    klab[j] = labels[b * NN + tok];
    kscr[j] = scores[b * NN + tok];
  }
  __syncthreads();

  // ---- focus ratio -> same_keep / cross_keep (uniform over rows/heads) ----
  if (tid < 8) {
    int c = 0;
    for (int i = 0; i < GSZ; ++i) c += (qlab[i] == tid);
    hist8[tid] = c;
  }
  __syncthreads();
  if (tid == 0) {
    int mode = 0, bc = hist8[0];
    for (int l = 1; l < 8; ++l)
      if (hist8[l] > bc) { bc = hist8[l]; mode = l; }
    (void)mode;
    float purity = (float)bc * (1.0f / GSZ);
    double mean = 0.0;
    for (int i = 0; i < GSZ; ++i) mean += (double)qscr[i];
    mean *= (1.0 / GSZ);
    double var = 0.0;
    for (int i = 0; i < GSZ; ++i) {
      double d = (double)qscr[i] - mean;
      var += d * d;
    }
    var *= (1.0 / GSZ);
    float focus = 0.5f + 0.25f * purity - 0.25f * (float)var;
    focus = fminf(fmaxf(focus, 0.25f), 0.75f);
    int keep = (int)ceilf(focus * (float)WSZ);
    keep = min(max(keep, 1), WSZ);
    // cross = round-half-even(keep/8), exact integer emulation
    int ck = keep >> 3, rem = keep & 7;
    if (rem > 4 || (rem == 4 && (ck & 1))) ck++;
    if (ck < 1) ck = 1;                       // keep > 1 always (keep >= 64)
    int sk = keep - ck;
    if (sk < 1) sk = 1;
    s_sk = sk;
    s_ck = ck;
  }
  __syncthreads();
  const int same_keep = s_sk, cross_keep = s_ck;

  const int row_i = tid >> 3, jx = tid & 7;  // QK/PV compute mapping
  const int dstage = tid & 63, rstage = tid >> 6;

  for (int c = 0; c < 4; ++c) {
    const int r0 = c * CHUNK;

    // ---- stage q chunk (32 x 64) ----
#pragma unroll
    for (int p = 0; p < CHUNK; p += 4)
      qbuf[rstage + p][dstage] =
          q[(size_t)(b * NN + g * GSZ + r0 + rstage + p) * DIMM + h * DH + dstage];

    // ---- QK^T: logits into att ----
    for (int jt = 0; jt < 4; ++jt) {
#pragma unroll
      for (int p = 0; p < 64; p += 4) {
        int j = jt * 64 + rstage + p;
        int pos = g * GSZ + j;
        int tok = pos < NN ? pos : (2 * NN - 1 - pos);
        ktile[rstage + p][dstage] = k[(size_t)(b * NN + tok) * DIMM + h * DH + dstage];
      }
      __syncthreads();
      float acc[8];
#pragma unroll
      for (int jj = 0; jj < 8; ++jj) acc[jj] = 0.f;
#pragma unroll
      for (int dd = 0; dd < DH; dd += 4) {
        float4 qv = *(const float4*)&qbuf[row_i][dd];
#pragma unroll
        for (int jj = 0; jj < 8; ++jj) {
          float4 kv = *(const float4*)&ktile[jx + 8 * jj][dd];
          acc[jj] += qv.x * kv.x + qv.y * kv.y + qv.z * kv.z + qv.w * kv.w;
        }
      }
#pragma unroll
      for (int jj = 0; jj < 8; ++jj)
        att[row_i][jt * 64 + jx + 8 * jj] = acc[jj] * 0.125f;
      __syncthreads();
    }

    // ---- softmax numerator a = exp(l - rowmax), in place ----
    // wave wv owns rows [wv*8, wv*8+8) for softmax AND ranking (lockstep safe)
    for (int s = 0; s < 8; ++s) {
      int rr = wv * 8 + s;
      float vals[4];
      float mx = -INFINITY;
#pragma unroll
      for (int m = 0; m < 4; ++m) {
        vals[m] = att[rr][lane + 64 * m];
        mx = fmaxf(mx, vals[m]);
      }
#pragma unroll
      for (int off = 32; off > 0; off >>= 1) mx = fmaxf(mx, __shfl_xor(mx, off));
#pragma unroll
      for (int m = 0; m < 4; ++m) vals[m] = expf(vals[m] - mx);
#pragma unroll
      for (int m = 0; m < 4; ++m) att[rr][lane + 64 * m] = vals[m];
    }
    // no barrier needed: same wave re-reads its own rows in ranking

    // ---- exact stable top-k (counting with u64 keys), 2 rows per wave ----
    for (int pr = 0; pr < 4; ++pr) {
      const int rr = wv * 8 + pr * 2 + (lane >> 5);
      const int jbase = lane & 31;
      const int qL = qlab[r0 + rr];
      const float qS = qscr[r0 + rr];

      unsigned long long skey[8], ckey[8];
      float avals[8];
      bool cand[8];
      int cs[8], cc[8];
#pragma unroll
      for (int m = 0; m < 8; ++m) {
        int j = jbase + 32 * m;
        float a = att[rr][j];
        avals[m] = a;
        float cv = a * (qS * kscr[j]);
        unsigned int lo = 0xFFFFFFFFu - (unsigned)j;
        skey[m] = ((unsigned long long)__float_as_uint(a) << 32) | lo;
        ckey[m] = ((unsigned long long)__float_as_uint(cv) << 32) | lo;
        cand[m] = (klab[j] == qL);
        cs[m] = 0;
        cc[m] = 0;
      }
#pragma unroll 4
      for (int t = 0; t < WSZ; ++t) {
        float a_t = att[rr][t];
        bool same_t = (klab[t] == qL);
        float c_t = a_t * (qS * kscr[t]);
        unsigned int lo_t = 0xFFFFFFFFu - (unsigned)t;
        unsigned long long sk_t =
            same_t ? (((unsigned long long)__float_as_uint(a_t) << 32) | lo_t) : 0ull;
        unsigned long long ck_t =
            ((unsigned long long)__float_as_uint(c_t) << 32) | lo_t;
#pragma unroll
        for (int m = 0; m < 8; ++m) {
          cs[m] += (sk_t > skey[m]);
          cc[m] += (ck_t > ckey[m]);
        }
      }
      // mask + renormalize over kept set
      float pv[8];
      float S = 0.f;
#pragma unroll
      for (int m = 0; m < 8; ++m) {
        bool kept = cand[m] ? (cs[m] < same_keep) : (cc[m] < cross_keep);
        pv[m] = kept ? avals[m] : 0.f;
        S += pv[m];
      }
#pragma unroll
      for (int off = 16; off > 0; off >>= 1) S += __shfl_xor(S, off);
      float inv = 1.0f / S;
#pragma unroll
      for (int m = 0; m < 8; ++m) att[rr][jbase + 32 * m] = pv[m] * inv;
    }
    __syncthreads();

    // ---- write attn_local chunk: (b, g, h, gs, ws) ----
    {
      size_t base = ((((size_t)b * NGRP + g) * HH + h) * GSZ + r0) * WSZ;
      for (int idx = tid; idx < CHUNK * WSZ; idx += 256) {
        int i = idx >> 8, j = idx & 255;
        attn_out[base + (size_t)i * WSZ + j] = att[i][j];
      }
    }

    // ---- PV: o_chunk = attn_local_chunk @ v_window ----
    const int dx = tid & 7;
    float oacc[8];
#pragma unroll
    for (int m = 0; m < 8; ++m) oacc[m] = 0.f;
    for (int jt = 0; jt < 4; ++jt) {
#pragma unroll
      for (int p = 0; p < 64; p += 4) {
        int j = jt * 64 + rstage + p;
        int pos = g * GSZ + j;
        int tok = pos < NN ? pos : (2 * NN - 1 - pos);
        ktile[rstage + p][dstage] = v[(size_t)(b * NN + tok) * DIMM + h * DH + dstage];
      }
      __syncthreads();
#pragma unroll 4
      for (int j = 0; j < 64; ++j) {
        float p_ = att[row_i][jt * 64 + j];
        float4 v0 = *(const float4*)&ktile[j][dx * 8];
        float4 v1 = *(const float4*)&ktile[j][dx * 8 + 4];
        oacc[0] += p_ * v0.x; oacc[1] += p_ * v0.y;
        oacc[2] += p_ * v0.z; oacc[3] += p_ * v0.w;
        oacc[4] += p_ * v1.x; oacc[5] += p_ * v1.y;
        oacc[6] += p_ * v1.z; oacc[7] += p_ * v1.w;
      }
      __syncthreads();
    }
    {
      size_t ob = (size_t)(b * NN + g * GSZ + r0 + row_i) * DIMM + h * DH + dx * 8;
      *(float4*)&o[ob] = make_float4(oacc[0], oacc[1], oacc[2], oacc[3]);
      *(float4*)&o[ob + 4] = make_float4(oacc[4], oacc[5], oacc[6], oacc[7]);
    }
    __syncthreads();
  }
}

// ---------------------------------------------------------------------------
extern "C" void kernel_launch(void* const* d_in, const int* in_sizes, int n_in,
                              void* d_out, int out_size, void* d_ws, size_t ws_size,
                              hipStream_t stream) {
  const float* x      = (const float*)d_in[0];
  const int*   labels = (const int*)d_in[1];
  const float* scores = (const float*)d_in[2];
  const float* Wq     = (const float*)d_in[3];
  const float* Wk     = (const float*)d_in[4];
  const float* Wv     = (const float*)d_in[5];
  const float* Wproj  = (const float*)d_in[6];

  float* out = (float*)d_out;                               // (B, N, DIM)
  float* attn_out = out + (size_t)BB * NN * DIMM;           // (B, ng, H, gs, ws)

  const size_t SZ = (size_t)BB * NN * DIMM;                 // 8388608
  float* qb = (float*)d_ws;
  float* kb = qb + SZ;
  float* vb = kb + SZ;

  gemm512<<<dim3(4, 128, 3), 256, 0, stream>>>(x, Wq, Wk, Wv, qb, kb, vb);
  attn_kernel<<<dim3(BB * NGRP * HH), 256, 0, stream>>>(qb, kb, vb, labels, scores,
                                                        attn_out, qb);
  gemm512<<<dim3(4, 128, 1), 256, 0, stream>>>(qb, Wproj, Wproj, Wproj, out, out, out);
}

// Round 2
// 1670.743 us; speedup vs baseline: 1.9419x; 1.9419x over previous
//
#include <hip/hip_runtime.h>

#define BB 4
#define NN 4096
#define DIMM 512
#define HH 8
#define DH 64
#define GSZ 128
#define NGRP 32
#define WSZ 256
#define CHUNK 32

// ---------------------------------------------------------------------------
// GEMM: C = A(16384x512) @ W(512x512); blockIdx.z selects among 3 W/C pairs.
// 128x128 tile, BK=32, 8x8 microtile per thread, 256 threads.
// ---------------------------------------------------------------------------
__global__ __launch_bounds__(256) void gemm512(
    const float* __restrict__ A,
    const float* __restrict__ W0, const float* __restrict__ W1, const float* __restrict__ W2,
    float* __restrict__ C0, float* __restrict__ C1, float* __restrict__ C2)
{
  const int z = blockIdx.z;
  const float* Wm = (z == 0) ? W0 : (z == 1 ? W1 : W2);
  float* Cm = (z == 0) ? C0 : (z == 1 ? C1 : C2);
  const int n0 = blockIdx.x * 128;
  const int m0 = blockIdx.y * 128;
  const int tid = threadIdx.x;
  const int tx = tid & 15, ty = tid >> 4;

  __shared__ float As[32][132];   // transposed A tile: As[k][m]
  __shared__ float Bs[32][132];   // Bs[k][n]

  float acc[8][8];
#pragma unroll
  for (int i = 0; i < 8; ++i)
#pragma unroll
    for (int j = 0; j < 8; ++j) acc[i][j] = 0.f;

  for (int k0 = 0; k0 < 512; k0 += 32) {
    {
      const int c4 = tid & 7, r = tid >> 3;
#pragma unroll
      for (int p = 0; p < 128; p += 32) {
        float4 av = *(const float4*)&A[(size_t)(m0 + r + p) * 512 + k0 + c4 * 4];
        As[c4 * 4 + 0][r + p] = av.x;
        As[c4 * 4 + 1][r + p] = av.y;
        As[c4 * 4 + 2][r + p] = av.z;
        As[c4 * 4 + 3][r + p] = av.w;
      }
      const int j4 = tid & 31, rb = tid >> 5;
#pragma unroll
      for (int p = 0; p < 32; p += 8) {
        *(float4*)&Bs[rb + p][j4 * 4] =
            *(const float4*)&Wm[(size_t)(k0 + rb + p) * 512 + n0 + j4 * 4];
      }
    }
    __syncthreads();
#pragma unroll
    for (int kk = 0; kk < 32; ++kk) {
      float4 a0 = *(const float4*)&As[kk][ty * 8];
      float4 a1 = *(const float4*)&As[kk][ty * 8 + 4];
      float4 b0 = *(const float4*)&Bs[kk][tx * 8];
      float4 b1 = *(const float4*)&Bs[kk][tx * 8 + 4];
      float av[8] = {a0.x, a0.y, a0.z, a0.w, a1.x, a1.y, a1.z, a1.w};
      float bv[8] = {b0.x, b0.y, b0.z, b0.w, b1.x, b1.y, b1.z, b1.w};
#pragma unroll
      for (int i = 0; i < 8; ++i)
#pragma unroll
        for (int j = 0; j < 8; ++j) acc[i][j] += av[i] * bv[j];
    }
    __syncthreads();
  }
#pragma unroll
  for (int i = 0; i < 8; ++i) {
    size_t row = (size_t)(m0 + ty * 8 + i);
    float4 o0 = make_float4(acc[i][0], acc[i][1], acc[i][2], acc[i][3]);
    float4 o1 = make_float4(acc[i][4], acc[i][5], acc[i][6], acc[i][7]);
    *(float4*)&Cm[row * 512 + n0 + tx * 8] = o0;
    *(float4*)&Cm[row * 512 + n0 + tx * 8 + 4] = o1;
  }
}

// ---------------------------------------------------------------------------
// Fused sparse attention. One block per (b, g, h, chunk-of-32-rows).
// 4096 blocks, c-major so a window's 4 chunks share an XCD (L2 reuse).
// Ranking: per-row MSB bisection on float-bit keys (exact, same kept set as
// the all-pairs u64 counting: value desc, then index asc via mbcnt tie pass).
// ---------------------------------------------------------------------------
__global__ __launch_bounds__(256) void attn_kernel(
    const float* q,                    // aliases o
    const float* __restrict__ k,
    const float* __restrict__ v,
    const int* __restrict__ labels,
    const float* __restrict__ scores,
    float* __restrict__ attn_out,
    float* o)                          // aliases q
{
  const int bx = blockIdx.x;
  const int c = bx >> 10;              // chunk 0..3 (slow dim -> same XCD per window)
  const int rblk = bx & 1023;
  const int h = rblk & 7;
  const int g = (rblk >> 3) & 31;
  const int b = rblk >> 8;
  const int r0 = c * CHUNK;
  const int tid = threadIdx.x;
  const int lane = tid & 63, wv = tid >> 6;

  __shared__ float att[CHUNK][WSZ + 4];    // 32 x 260 : logits -> final p
  __shared__ float qbuf[CHUNK][DH + 4];    // 32 x 68
  __shared__ float ktile[64][DH + 4];      // 64 x 68 (k, then v)
  __shared__ int klab[WSZ];
  __shared__ float kscr[WSZ];
  __shared__ int hist8[8];
  __shared__ int s_sk, s_ck;

  // ---- labels / scores (window map: pos>=N -> 2N-1-pos, the flipped tail) ----
  {
    int j = tid;  // 256 threads == WSZ
    int pos = g * GSZ + j;
    int tok = pos < NN ? pos : (2 * NN - 1 - pos);
    klab[j] = labels[b * NN + tok];
    kscr[j] = scores[b * NN + tok];
  }
  __syncthreads();

  // ---- focus ratio -> same_keep / cross_keep (group-level: window[0..127]) ----
  if (tid < 8) {
    int cnt = 0;
    for (int i = 0; i < GSZ; ++i) cnt += (klab[i] == tid);
    hist8[tid] = cnt;
  }
  __syncthreads();
  if (tid == 0) {
    int bc = hist8[0];
    for (int l = 1; l < 8; ++l)
      if (hist8[l] > bc) bc = hist8[l];
    float purity = (float)bc * (1.0f / GSZ);
    double mean = 0.0;
    for (int i = 0; i < GSZ; ++i) mean += (double)kscr[i];
    mean *= (1.0 / GSZ);
    double var = 0.0;
    for (int i = 0; i < GSZ; ++i) {
      double d = (double)kscr[i] - mean;
      var += d * d;
    }
    var *= (1.0 / GSZ);
    float focus = 0.5f + 0.25f * purity - 0.25f * (float)var;
    focus = fminf(fmaxf(focus, 0.25f), 0.75f);
    int keep = (int)ceilf(focus * (float)WSZ);
    keep = min(max(keep, 1), WSZ);
    int ck = keep >> 3, rem = keep & 7;          // round-half-even(keep/8)
    if (rem > 4 || (rem == 4 && (ck & 1))) ck++;
    if (ck < 1) ck = 1;
    int sk = keep - ck;
    if (sk < 1) sk = 1;
    s_sk = sk;
    s_ck = ck;
  }
  __syncthreads();
  const int same_keep = s_sk, cross_keep = s_ck;

  const int row_i = tid >> 3, jx = tid & 7;  // QK/PV compute mapping
  const int dstage = tid & 63, rstage = tid >> 6;

  // ---- stage q chunk (32 x 64) ----
#pragma unroll
  for (int p = 0; p < CHUNK; p += 4)
    qbuf[rstage + p][dstage] =
        q[(size_t)(b * NN + g * GSZ + r0 + rstage + p) * DIMM + h * DH + dstage];

  // ---- QK^T: logits into att ----
  for (int jt = 0; jt < 4; ++jt) {
#pragma unroll
    for (int p = 0; p < 64; p += 4) {
      int j = jt * 64 + rstage + p;
      int pos = g * GSZ + j;
      int tok = pos < NN ? pos : (2 * NN - 1 - pos);
      ktile[rstage + p][dstage] = k[(size_t)(b * NN + tok) * DIMM + h * DH + dstage];
    }
    __syncthreads();
    float acc[8];
#pragma unroll
    for (int jj = 0; jj < 8; ++jj) acc[jj] = 0.f;
#pragma unroll
    for (int dd = 0; dd < DH; dd += 4) {
      float4 qv = *(const float4*)&qbuf[row_i][dd];
#pragma unroll
      for (int jj = 0; jj < 8; ++jj) {
        float4 kv = *(const float4*)&ktile[jx + 8 * jj][dd];
        acc[jj] += qv.x * kv.x + qv.y * kv.y + qv.z * kv.z + qv.w * kv.w;
      }
    }
#pragma unroll
    for (int jj = 0; jj < 8; ++jj)
      att[row_i][jt * 64 + jx + 8 * jj] = acc[jj] * 0.125f;
    __syncthreads();
  }

  // ---- fused softmax + exact top-k (bisection) + renorm, wave-per-row ----
  {
    int kl0[4];
    float ks0[4];
#pragma unroll
    for (int m = 0; m < 4; ++m) {
      kl0[m] = klab[lane + 64 * m];
      ks0[m] = kscr[lane + 64 * m];
    }
    for (int s = 0; s < 8; ++s) {
      const int rr = wv * 8 + s;
      const int qL = klab[r0 + rr];
      const float qS = kscr[r0 + rr];
      float a[4];
      float mx = -INFINITY;
#pragma unroll
      for (int m = 0; m < 4; ++m) {
        a[m] = att[rr][lane + 64 * m];
        mx = fmaxf(mx, a[m]);
      }
#pragma unroll
      for (int off = 32; off > 0; off >>= 1) mx = fmaxf(mx, __shfl_xor(mx, off));
      unsigned fs[4], fc[4];
      bool cand[4];
#pragma unroll
      for (int m = 0; m < 4; ++m) {
        a[m] = expf(a[m] - mx);                       // a in (0,1] -> bits < 2^30
        cand[m] = (kl0[m] == qL);
        fs[m] = cand[m] ? __float_as_uint(a[m]) : 0u;
        fc[m] = __float_as_uint(a[m] * (qS * ks0[m]));
      }
      // bisect: max t with count(bits >= t) >= keep  == keep-th largest value
      unsigned ts = 0, tc = 0;
      for (int bit = 29; bit >= 0; --bit) {
        unsigned cs = ts | (1u << bit), cc = tc | (1u << bit);
        int ns = 0, nc = 0;
#pragma unroll
        for (int m = 0; m < 4; ++m) {
          ns += __popcll(__ballot(fs[m] >= cs));
          nc += __popcll(__ballot(fc[m] >= cc));
        }
        if (ns >= same_keep) ts = cs;
        if (nc >= cross_keep) tc = cc;
      }
      // exact index tie-break among value-equals (smaller j wins; j = lane+64m)
      unsigned long long beqs[4], beqc[4];
      int gts = 0, gtc = 0;
#pragma unroll
      for (int m = 0; m < 4; ++m) {
        gts += __popcll(__ballot(fs[m] > ts));
        gtc += __popcll(__ballot(fc[m] > tc));
        beqs[m] = __ballot(fs[m] == ts);
        beqc[m] = __ballot(fc[m] == tc);
      }
      const int rs = same_keep - gts, rc = cross_keep - gtc;
      float pv[4];
      float S = 0.f;
      int pres = 0, prec = 0;
#pragma unroll
      for (int m = 0; m < 4; ++m) {
        int mbs = __builtin_amdgcn_mbcnt_hi((unsigned)(beqs[m] >> 32),
                   __builtin_amdgcn_mbcnt_lo((unsigned)beqs[m], 0));
        int mbc = __builtin_amdgcn_mbcnt_hi((unsigned)(beqc[m] >> 32),
                   __builtin_amdgcn_mbcnt_lo((unsigned)beqc[m], 0));
        bool keep_s = cand[m] && ((fs[m] > ts) || ((fs[m] == ts) && (pres + mbs < rs)));
        bool keep_c = (!cand[m]) && ((fc[m] > tc) || ((fc[m] == tc) && (prec + mbc < rc)));
        pv[m] = (keep_s || keep_c) ? a[m] : 0.f;
        S += pv[m];
        pres += __popcll(beqs[m]);
        prec += __popcll(beqc[m]);
      }
#pragma unroll
      for (int off = 32; off > 0; off >>= 1) S += __shfl_xor(S, off);
      const float inv = 1.0f / S;
      size_t gb = ((((size_t)b * NGRP + g) * HH + h) * GSZ + (r0 + rr)) * WSZ + lane;
#pragma unroll
      for (int m = 0; m < 4; ++m) {
        float p = pv[m] * inv;
        att[rr][lane + 64 * m] = p;
        attn_out[gb + 64 * m] = p;
      }
    }
  }
  __syncthreads();

  // ---- PV: o_chunk = attn_local_chunk @ v_window ----
  const int dx = tid & 7;
  float oacc[8];
#pragma unroll
  for (int m = 0; m < 8; ++m) oacc[m] = 0.f;
  for (int jt = 0; jt < 4; ++jt) {
#pragma unroll
    for (int p = 0; p < 64; p += 4) {
      int j = jt * 64 + rstage + p;
      int pos = g * GSZ + j;
      int tok = pos < NN ? pos : (2 * NN - 1 - pos);
      ktile[rstage + p][dstage] = v[(size_t)(b * NN + tok) * DIMM + h * DH + dstage];
    }
    __syncthreads();
#pragma unroll 4
    for (int j = 0; j < 64; ++j) {
      float p_ = att[row_i][jt * 64 + j];
      float4 v0 = *(const float4*)&ktile[j][dx * 8];
      float4 v1 = *(const float4*)&ktile[j][dx * 8 + 4];
      oacc[0] += p_ * v0.x; oacc[1] += p_ * v0.y;
      oacc[2] += p_ * v0.z; oacc[3] += p_ * v0.w;
      oacc[4] += p_ * v1.x; oacc[5] += p_ * v1.y;
      oacc[6] += p_ * v1.z; oacc[7] += p_ * v1.w;
    }
    __syncthreads();
  }
  {
    size_t ob = (size_t)(b * NN + g * GSZ + r0 + row_i) * DIMM + h * DH + dx * 8;
    *(float4*)&o[ob] = make_float4(oacc[0], oacc[1], oacc[2], oacc[3]);
    *(float4*)&o[ob + 4] = make_float4(oacc[4], oacc[5], oacc[6], oacc[7]);
  }
}

// ---------------------------------------------------------------------------
extern "C" void kernel_launch(void* const* d_in, const int* in_sizes, int n_in,
                              void* d_out, int out_size, void* d_ws, size_t ws_size,
                              hipStream_t stream) {
  const float* x      = (const float*)d_in[0];
  const int*   labels = (const int*)d_in[1];
  const float* scores = (const float*)d_in[2];
  const float* Wq     = (const float*)d_in[3];
  const float* Wk     = (const float*)d_in[4];
  const float* Wv     = (const float*)d_in[5];
  const float* Wproj  = (const float*)d_in[6];

  float* out = (float*)d_out;                               // (B, N, DIM)
  float* attn_out = out + (size_t)BB * NN * DIMM;           // (B, ng, H, gs, ws)

  const size_t SZ = (size_t)BB * NN * DIMM;                 // 8388608
  float* qb = (float*)d_ws;
  float* kb = qb + SZ;
  float* vb = kb + SZ;

  gemm512<<<dim3(4, 128, 3), 256, 0, stream>>>(x, Wq, Wk, Wv, qb, kb, vb);
  attn_kernel<<<dim3(BB * NGRP * HH * 4), 256, 0, stream>>>(qb, kb, vb, labels, scores,
                                                            attn_out, qb);
  gemm512<<<dim3(4, 128, 1), 256, 0, stream>>>(qb, Wproj, Wproj, Wproj, out, out, out);
}

// Round 3
// 1116.794 us; speedup vs baseline: 2.9050x; 1.4960x over previous
//
#include <hip/hip_runtime.h>

#define BB 4
#define NN 4096
#define DIMM 512
#define HH 8
#define DH 64
#define GSZ 128
#define NGRP 32
#define WSZ 256
#define CHUNK 32

// ---------------------------------------------------------------------------
// GEMM: C = A(16384x512) @ W(512x512); blockIdx.z selects among 3 W/C pairs.
// 128x128 tile, BK=32, 8x8 microtile per thread, 256 threads.
// ---------------------------------------------------------------------------
__global__ __launch_bounds__(256) void gemm512(
    const float* __restrict__ A,
    const float* __restrict__ W0, const float* __restrict__ W1, const float* __restrict__ W2,
    float* __restrict__ C0, float* __restrict__ C1, float* __restrict__ C2)
{
  const int z = blockIdx.z;
  const float* Wm = (z == 0) ? W0 : (z == 1 ? W1 : W2);
  float* Cm = (z == 0) ? C0 : (z == 1 ? C1 : C2);
  const int n0 = blockIdx.x * 128;
  const int m0 = blockIdx.y * 128;
  const int tid = threadIdx.x;
  const int tx = tid & 15, ty = tid >> 4;

  __shared__ float As[32][132];   // transposed A tile: As[k][m]
  __shared__ float Bs[32][132];   // Bs[k][n]

  float acc[8][8];
#pragma unroll
  for (int i = 0; i < 8; ++i)
#pragma unroll
    for (int j = 0; j < 8; ++j) acc[i][j] = 0.f;

  for (int k0 = 0; k0 < 512; k0 += 32) {
    {
      const int c4 = tid & 7, r = tid >> 3;
#pragma unroll
      for (int p = 0; p < 128; p += 32) {
        float4 av = *(const float4*)&A[(size_t)(m0 + r + p) * 512 + k0 + c4 * 4];
        As[c4 * 4 + 0][r + p] = av.x;
        As[c4 * 4 + 1][r + p] = av.y;
        As[c4 * 4 + 2][r + p] = av.z;
        As[c4 * 4 + 3][r + p] = av.w;
      }
      const int j4 = tid & 31, rb = tid >> 5;
#pragma unroll
      for (int p = 0; p < 32; p += 8) {
        *(float4*)&Bs[rb + p][j4 * 4] =
            *(const float4*)&Wm[(size_t)(k0 + rb + p) * 512 + n0 + j4 * 4];
      }
    }
    __syncthreads();
#pragma unroll
    for (int kk = 0; kk < 32; ++kk) {
      float4 a0 = *(const float4*)&As[kk][ty * 8];
      float4 a1 = *(const float4*)&As[kk][ty * 8 + 4];
      float4 b0 = *(const float4*)&Bs[kk][tx * 8];
      float4 b1 = *(const float4*)&Bs[kk][tx * 8 + 4];
      float av[8] = {a0.x, a0.y, a0.z, a0.w, a1.x, a1.y, a1.z, a1.w};
      float bv[8] = {b0.x, b0.y, b0.z, b0.w, b1.x, b1.y, b1.z, b1.w};
#pragma unroll
      for (int i = 0; i < 8; ++i)
#pragma unroll
        for (int j = 0; j < 8; ++j) acc[i][j] += av[i] * bv[j];
    }
    __syncthreads();
  }
#pragma unroll
  for (int i = 0; i < 8; ++i) {
    size_t row = (size_t)(m0 + ty * 8 + i);
    float4 o0 = make_float4(acc[i][0], acc[i][1], acc[i][2], acc[i][3]);
    float4 o1 = make_float4(acc[i][4], acc[i][5], acc[i][6], acc[i][7]);
    *(float4*)&Cm[row * 512 + n0 + tx * 8] = o0;
    *(float4*)&Cm[row * 512 + n0 + tx * 8 + 4] = o1;
  }
}

// ---------------------------------------------------------------------------
// Fused sparse attention. One block per (b, g, h, chunk-of-32-rows).
// 256 threads. LDS 51.5 KB -> 3 blocks/CU. QK/PV use 2-row register tiles
// (6 ds_read_b128 per 32-64 FMA). Ranking: exact MSB bisection (unchanged).
// ---------------------------------------------------------------------------
__global__ __launch_bounds__(256, 3) void attn_kernel(
    const float* q,                    // aliases o
    const float* __restrict__ k,
    const float* __restrict__ v,
    const int* __restrict__ labels,
    const float* __restrict__ scores,
    float* __restrict__ attn_out,
    float* o)                          // aliases q
{
  const int bx = blockIdx.x;
  const int c = bx >> 10;              // chunk 0..3
  const int rblk = bx & 1023;
  const int h = rblk & 7;
  const int g = (rblk >> 3) & 31;
  const int b = rblk >> 8;
  const int r0 = c * CHUNK;
  const int tid = threadIdx.x;
  const int lane = tid & 63, wv = tid >> 6;

  __shared__ float att[CHUNK][WSZ + 4];    // 32 x 260 : logits -> final p
  __shared__ float ktile[64][DH + 4];      // 64 x 68 (k, then v)
  __shared__ int klab[WSZ];
  __shared__ float kscr[WSZ];
  __shared__ int hist8[8];
  __shared__ int s_sk, s_ck;

  // ---- labels / scores (window map: pos>=N -> 2N-1-pos, the flipped tail) ----
  {
    int j = tid;  // 256 threads == WSZ
    int pos = g * GSZ + j;
    int tok = pos < NN ? pos : (2 * NN - 1 - pos);
    klab[j] = labels[b * NN + tok];
    kscr[j] = scores[b * NN + tok];
  }
  __syncthreads();

  // ---- focus ratio -> same_keep / cross_keep (group-level: window[0..127]) ----
  if (tid < 8) {
    int cnt = 0;
    for (int i = 0; i < GSZ; ++i) cnt += (klab[i] == tid);
    hist8[tid] = cnt;
  }
  __syncthreads();
  if (tid == 0) {
    int bc = hist8[0];
    for (int l = 1; l < 8; ++l)
      if (hist8[l] > bc) bc = hist8[l];
    float purity = (float)bc * (1.0f / GSZ);
    double mean = 0.0;
    for (int i = 0; i < GSZ; ++i) mean += (double)kscr[i];
    mean *= (1.0 / GSZ);
    double var = 0.0;
    for (int i = 0; i < GSZ; ++i) {
      double d = (double)kscr[i] - mean;
      var += d * d;
    }
    var *= (1.0 / GSZ);
    float focus = 0.5f + 0.25f * purity - 0.25f * (float)var;
    focus = fminf(fmaxf(focus, 0.25f), 0.75f);
    int keep = (int)ceilf(focus * (float)WSZ);
    keep = min(max(keep, 1), WSZ);
    int ck = keep >> 3, rem = keep & 7;          // round-half-even(keep/8)
    if (rem > 4 || (rem == 4 && (ck & 1))) ck++;
    if (ck < 1) ck = 1;
    int sk = keep - ck;
    if (sk < 1) sk = 1;
    s_sk = sk;
    s_ck = ck;
  }
  __syncthreads();
  const int same_keep = s_sk, cross_keep = s_ck;

  const int rp = tid >> 4, jx = tid & 15;    // QK/PV compute mapping (rows rp, rp+16)
  const int dstage = tid & 63, rstage = tid >> 6;

  const float* q0p = q + (size_t)(b * NN + g * GSZ + r0 + rp) * DIMM + h * DH;
  const float* q1p = q0p + (size_t)16 * DIMM;

  // ---- QK^T: logits into att (2 rows x 4 cols per thread) ----
  for (int jt = 0; jt < 4; ++jt) {
#pragma unroll
    for (int p = 0; p < 64; p += 4) {
      int j = jt * 64 + rstage + p;
      int pos = g * GSZ + j;
      int tok = pos < NN ? pos : (2 * NN - 1 - pos);
      ktile[rstage + p][dstage] = k[(size_t)(b * NN + tok) * DIMM + h * DH + dstage];
    }
    __syncthreads();
    float acc0[4] = {0.f, 0.f, 0.f, 0.f}, acc1[4] = {0.f, 0.f, 0.f, 0.f};
#pragma unroll
    for (int dd = 0; dd < DH; dd += 4) {
      float4 q0 = *(const float4*)(q0p + dd);
      float4 q1 = *(const float4*)(q1p + dd);
#pragma unroll
      for (int jj = 0; jj < 4; ++jj) {
        float4 kv = *(const float4*)&ktile[jx + 16 * jj][dd];
        acc0[jj] += q0.x * kv.x + q0.y * kv.y + q0.z * kv.z + q0.w * kv.w;
        acc1[jj] += q1.x * kv.x + q1.y * kv.y + q1.z * kv.z + q1.w * kv.w;
      }
    }
#pragma unroll
    for (int jj = 0; jj < 4; ++jj) {
      att[rp][jt * 64 + jx + 16 * jj] = acc0[jj] * 0.125f;
      att[rp + 16][jt * 64 + jx + 16 * jj] = acc1[jj] * 0.125f;
    }
    __syncthreads();
  }

  // ---- fused softmax + exact top-k (bisection) + renorm, wave-per-row ----
  {
    int kl0[4];
    float ks0[4];
#pragma unroll
    for (int m = 0; m < 4; ++m) {
      kl0[m] = klab[lane + 64 * m];
      ks0[m] = kscr[lane + 64 * m];
    }
    for (int s = 0; s < 8; ++s) {
      const int rr = wv * 8 + s;
      const int qL = klab[r0 + rr];
      const float qS = kscr[r0 + rr];
      float a[4];
      float mx = -INFINITY;
#pragma unroll
      for (int m = 0; m < 4; ++m) {
        a[m] = att[rr][lane + 64 * m];
        mx = fmaxf(mx, a[m]);
      }
#pragma unroll
      for (int off = 32; off > 0; off >>= 1) mx = fmaxf(mx, __shfl_xor(mx, off));
      unsigned fs[4], fc[4];
      bool cand[4];
#pragma unroll
      for (int m = 0; m < 4; ++m) {
        a[m] = expf(a[m] - mx);                       // a in (0,1] -> bits < 2^30
        cand[m] = (kl0[m] == qL);
        fs[m] = cand[m] ? __float_as_uint(a[m]) : 0u;
        fc[m] = __float_as_uint(a[m] * (qS * ks0[m]));
      }
      // bisect: max t with count(bits >= t) >= keep  == keep-th largest value
      unsigned ts = 0, tc = 0;
      for (int bit = 29; bit >= 0; --bit) {
        unsigned cs = ts | (1u << bit), cc = tc | (1u << bit);
        int ns = 0, nc = 0;
#pragma unroll
        for (int m = 0; m < 4; ++m) {
          ns += __popcll(__ballot(fs[m] >= cs));
          nc += __popcll(__ballot(fc[m] >= cc));
        }
        if (ns >= same_keep) ts = cs;
        if (nc >= cross_keep) tc = cc;
      }
      // exact index tie-break among value-equals (smaller j wins; j = lane+64m)
      unsigned long long beqs[4], beqc[4];
      int gts = 0, gtc = 0;
#pragma unroll
      for (int m = 0; m < 4; ++m) {
        gts += __popcll(__ballot(fs[m] > ts));
        gtc += __popcll(__ballot(fc[m] > tc));
        beqs[m] = __ballot(fs[m] == ts);
        beqc[m] = __ballot(fc[m] == tc);
      }
      const int rs = same_keep - gts, rc = cross_keep - gtc;
      float pv[4];
      float S = 0.f;
      int pres = 0, prec = 0;
#pragma unroll
      for (int m = 0; m < 4; ++m) {
        int mbs = __builtin_amdgcn_mbcnt_hi((unsigned)(beqs[m] >> 32),
                   __builtin_amdgcn_mbcnt_lo((unsigned)beqs[m], 0));
        int mbc = __builtin_amdgcn_mbcnt_hi((unsigned)(beqc[m] >> 32),
                   __builtin_amdgcn_mbcnt_lo((unsigned)beqc[m], 0));
        bool keep_s = cand[m] && ((fs[m] > ts) || ((fs[m] == ts) && (pres + mbs < rs)));
        bool keep_c = (!cand[m]) && ((fc[m] > tc) || ((fc[m] == tc) && (prec + mbc < rc)));
        pv[m] = (keep_s || keep_c) ? a[m] : 0.f;
        S += pv[m];
        pres += __popcll(beqs[m]);
        prec += __popcll(beqc[m]);
      }
#pragma unroll
      for (int off = 32; off > 0; off >>= 1) S += __shfl_xor(S, off);
      const float inv = 1.0f / S;
      size_t gb = ((((size_t)b * NGRP + g) * HH + h) * GSZ + (r0 + rr)) * WSZ + lane;
#pragma unroll
      for (int m = 0; m < 4; ++m) {
        float p = pv[m] * inv;
        att[rr][lane + 64 * m] = p;
        attn_out[gb + 64 * m] = p;
      }
    }
  }
  __syncthreads();

  // ---- PV: o_chunk = p @ v_window (2 rows x 4 d per thread, j-blocked 4) ----
  const int dx = jx;
  float oa0[4] = {0.f, 0.f, 0.f, 0.f}, oa1[4] = {0.f, 0.f, 0.f, 0.f};
  for (int jt = 0; jt < 4; ++jt) {
#pragma unroll
    for (int p = 0; p < 64; p += 4) {
      int j = jt * 64 + rstage + p;
      int pos = g * GSZ + j;
      int tok = pos < NN ? pos : (2 * NN - 1 - pos);
      ktile[rstage + p][dstage] = v[(size_t)(b * NN + tok) * DIMM + h * DH + dstage];
    }
    __syncthreads();
#pragma unroll 4
    for (int jg = 0; jg < 16; ++jg) {
      float4 p0 = *(const float4*)&att[rp][jt * 64 + jg * 4];
      float4 p1 = *(const float4*)&att[rp + 16][jt * 64 + jg * 4];
      float4 v0 = *(const float4*)&ktile[jg * 4 + 0][dx * 4];
      float4 v1 = *(const float4*)&ktile[jg * 4 + 1][dx * 4];
      float4 v2 = *(const float4*)&ktile[jg * 4 + 2][dx * 4];
      float4 v3 = *(const float4*)&ktile[jg * 4 + 3][dx * 4];
      oa0[0] += p0.x * v0.x + p0.y * v1.x + p0.z * v2.x + p0.w * v3.x;
      oa0[1] += p0.x * v0.y + p0.y * v1.y + p0.z * v2.y + p0.w * v3.y;
      oa0[2] += p0.x * v0.z + p0.y * v1.z + p0.z * v2.z + p0.w * v3.z;
      oa0[3] += p0.x * v0.w + p0.y * v1.w + p0.z * v2.w + p0.w * v3.w;
      oa1[0] += p1.x * v0.x + p1.y * v1.x + p1.z * v2.x + p1.w * v3.x;
      oa1[1] += p1.x * v0.y + p1.y * v1.y + p1.z * v2.y + p1.w * v3.y;
      oa1[2] += p1.x * v0.z + p1.y * v1.z + p1.z * v2.z + p1.w * v3.z;
      oa1[3] += p1.x * v0.w + p1.y * v1.w + p1.z * v2.w + p1.w * v3.w;
    }
    __syncthreads();
  }
  {
    size_t ob0 = (size_t)(b * NN + g * GSZ + r0 + rp) * DIMM + h * DH + dx * 4;
    *(float4*)&o[ob0] = make_float4(oa0[0], oa0[1], oa0[2], oa0[3]);
    *(float4*)&o[ob0 + (size_t)16 * DIMM] = make_float4(oa1[0], oa1[1], oa1[2], oa1[3]);
  }
}

// ---------------------------------------------------------------------------
extern "C" void kernel_launch(void* const* d_in, const int* in_sizes, int n_in,
                              void* d_out, int out_size, void* d_ws, size_t ws_size,
                              hipStream_t stream) {
  const float* x      = (const float*)d_in[0];
  const int*   labels = (const int*)d_in[1];
  const float* scores = (const float*)d_in[2];
  const float* Wq     = (const float*)d_in[3];
  const float* Wk     = (const float*)d_in[4];
  const float* Wv     = (const float*)d_in[5];
  const float* Wproj  = (const float*)d_in[6];

  float* out = (float*)d_out;                               // (B, N, DIM)
  float* attn_out = out + (size_t)BB * NN * DIMM;           // (B, ng, H, gs, ws)

  const size_t SZ = (size_t)BB * NN * DIMM;                 // 8388608
  float* qb = (float*)d_ws;
  float* kb = qb + SZ;
  float* vb = kb + SZ;

  gemm512<<<dim3(4, 128, 3), 256, 0, stream>>>(x, Wq, Wk, Wv, qb, kb, vb);
  attn_kernel<<<dim3(BB * NGRP * HH * 4), 256, 0, stream>>>(qb, kb, vb, labels, scores,
                                                            attn_out, qb);
  gemm512<<<dim3(4, 128, 1), 256, 0, stream>>>(qb, Wproj, Wproj, Wproj, out, out, out);
}

// Round 4
// 966.419 us; speedup vs baseline: 3.3571x; 1.1556x over previous
//
#include <hip/hip_runtime.h>

#define BB 4
#define NN 4096
#define DIMM 512
#define HH 8
#define DH 64
#define GSZ 128
#define NGRP 32
#define WSZ 256
#define CHUNK 32

#define MK 8388608u     // 16384*512 elements (x / q / k / v / o planes)
#define WK 262144u      // 512*512

typedef short short8 __attribute__((ext_vector_type(8)));
typedef float f32x4 __attribute__((ext_vector_type(4)));

__device__ inline unsigned short bf16rne(float f) {
  unsigned u = __float_as_uint(f);
  unsigned r = u + 0x7FFFu + ((u >> 16) & 1u);
  return (unsigned short)(r >> 16);
}
__device__ inline float bf16tof(unsigned short h) {
  return __uint_as_float(((unsigned)h) << 16);
}

// ---------------------------------------------------------------------------
// split_planes: fp32 -> 2 or 3 bf16 planes (hi, mid[, lo]); exact residual split
// ---------------------------------------------------------------------------
__global__ __launch_bounds__(256) void split_planes(
    const float* __restrict__ X, unsigned short* __restrict__ P, int np)
{
  unsigned idx = (blockIdx.x * 256u + threadIdx.x) * 4u;
  float4 xv = *(const float4*)&X[idx];
  float xs[4] = {xv.x, xv.y, xv.z, xv.w};
  ushort4 hv, mv, lv;
  unsigned short* hp = (unsigned short*)&hv;
  unsigned short* mp = (unsigned short*)&mv;
  unsigned short* lp = (unsigned short*)&lv;
#pragma unroll
  for (int i = 0; i < 4; ++i) {
    unsigned short h = bf16rne(xs[i]);
    float r1 = xs[i] - bf16tof(h);
    unsigned short m = bf16rne(r1);
    float r2 = r1 - bf16tof(m);
    hp[i] = h;
    mp[i] = m;
    lp[i] = bf16rne(r2);
  }
  *(ushort4*)&P[idx] = hv;
  *(ushort4*)&P[MK + idx] = mv;
  if (np == 3) *(ushort4*)&P[2u * MK + idx] = lv;
}

// ---------------------------------------------------------------------------
// split_w: weights -> transposed (N x K) bf16 planes.
// Wq,Wk,Wv -> wqkv[z][3 planes]; Wproj -> wproj[2 planes].
// ---------------------------------------------------------------------------
__global__ __launch_bounds__(256) void split_w(
    const float* __restrict__ Wq, const float* __restrict__ Wk,
    const float* __restrict__ Wv, const float* __restrict__ Wpj,
    unsigned short* __restrict__ wqkv, unsigned short* __restrict__ wproj)
{
  unsigned e = blockIdx.x * 256u + threadIdx.x;     // over 4 * 2^18
  int mz = e >> 18;
  unsigned rem = e & (WK - 1u);
  unsigned kk = rem >> 9, n = rem & 511u;
  const float* src = (mz == 0) ? Wq : (mz == 1) ? Wk : (mz == 2) ? Wv : Wpj;
  float w = src[kk * 512u + n];
  unsigned short h = bf16rne(w);
  float r1 = w - bf16tof(h);
  unsigned short m = bf16rne(r1);
  float r2 = r1 - bf16tof(m);
  unsigned short l = bf16rne(r2);
  unsigned o = n * 512u + kk;
  if (mz < 3) {
    unsigned short* base = wqkv + (unsigned)mz * 3u * WK;
    base[o] = h;
    base[WK + o] = m;
    base[2u * WK + o] = l;
  } else {
    wproj[o] = h;
    wproj[WK + o] = m;
  }
}

// ---------------------------------------------------------------------------
// mfma_gemm: C[z] = A(16384x512) @ W[z](512x512) via split-bf16 MFMA.
// NP planes per operand staged in LDS; NT term products accumulated.
// 128x128 tile, BK=32, 4 waves, 4x4 frags of 16x16x32 per wave.
// Layouts (HW-verified per guide): A-frag A[m=lane&15][k=(lane>>4)*8+j],
// B-frag from W^T rows (n=lane&15), C/D col=lane&15 row=(lane>>4)*4+reg.
// ---------------------------------------------------------------------------
template <int NP, int NT>
__global__ __launch_bounds__(256) void mfma_gemm(
    const unsigned short* __restrict__ Ap,   // NP planes, plane stride MK
    const unsigned short* __restrict__ Wp,   // [z][NP][n][k], plane stride WK
    float* __restrict__ C)                   // + z * 8388608
{
  constexpr int ta[6] = {0, 0, 1, 1, 0, 2};
  constexpr int tw[6] = {0, 1, 0, 1, 2, 0};
  const int z = blockIdx.z;
  const int n0 = blockIdx.x * 128;
  const int m0 = blockIdx.y * 128;
  const int tid = threadIdx.x;
  const int lane = tid & 63, wv = tid >> 6;
  const int wm = (wv >> 1) * 64, wn = (wv & 1) * 64;
  const int lm = lane & 15, lk = (lane >> 4) * 8;

  __shared__ unsigned short As[NP * 128 * 40];   // stride 40 bf16 = 80 B
  __shared__ unsigned short Ws[NP * 128 * 40];

  f32x4 acc[4][4];
#pragma unroll
  for (int i = 0; i < 4; ++i)
#pragma unroll
    for (int j = 0; j < 4; ++j) acc[i][j] = (f32x4){0.f, 0.f, 0.f, 0.f};

  const unsigned short* Wz = Wp + (size_t)z * NP * WK;

  for (int k0 = 0; k0 < 512; k0 += 32) {
#pragma unroll
    for (int i = 0; i < NP * 2; ++i) {           // NP*512 16B-chunks each side
      int idx = i * 256 + tid;
      int p = idx >> 9, rem = idx & 511;
      int r = rem >> 2, cc = rem & 3;
      *(short8*)&As[p * 5120 + r * 40 + cc * 8] =
          *(const short8*)&Ap[(size_t)p * MK + (size_t)(m0 + r) * 512 + k0 + cc * 8];
      *(short8*)&Ws[p * 5120 + r * 40 + cc * 8] =
          *(const short8*)&Wz[(size_t)p * WK + (size_t)(n0 + r) * 512 + k0 + cc * 8];
    }
    __syncthreads();

    short8 a[NP][4];
#pragma unroll
    for (int p = 0; p < NP; ++p)
#pragma unroll
      for (int fm = 0; fm < 4; ++fm)
        a[p][fm] = *(const short8*)&As[p * 5120 + (wm + fm * 16 + lm) * 40 + lk];

#pragma unroll
    for (int fn = 0; fn < 4; ++fn) {
      short8 bf[NP];
#pragma unroll
      for (int p = 0; p < NP; ++p)
        bf[p] = *(const short8*)&Ws[p * 5120 + (wn + fn * 16 + lm) * 40 + lk];
#pragma unroll
      for (int fm = 0; fm < 4; ++fm) {
#pragma unroll
        for (int t = 0; t < NT; ++t)
          acc[fm][fn] = __builtin_amdgcn_mfma_f32_16x16x32_bf16(
              a[ta[t]][fm], bf[tw[t]], acc[fm][fn], 0, 0, 0);
      }
    }
    __syncthreads();
  }

  float* Cz = C + (size_t)z * 8388608u;
  const int rq = (lane >> 4) * 4;
#pragma unroll
  for (int fm = 0; fm < 4; ++fm)
#pragma unroll
    for (int fn = 0; fn < 4; ++fn) {
      int row = m0 + wm + fm * 16 + rq;
      int col = n0 + wn + fn * 16 + lm;
#pragma unroll
      for (int r = 0; r < 4; ++r)
        Cz[(size_t)(row + r) * 512 + col] = acc[fm][fn][r];
    }
}

// ---------------------------------------------------------------------------
// Fallback fp32 GEMM (used only if ws_size can't hold the bf16 planes).
// ---------------------------------------------------------------------------
__global__ __launch_bounds__(256) void gemm512(
    const float* __restrict__ A,
    const float* __restrict__ W0, const float* __restrict__ W1, const float* __restrict__ W2,
    float* __restrict__ C0, float* __restrict__ C1, float* __restrict__ C2)
{
  const int z = blockIdx.z;
  const float* Wm = (z == 0) ? W0 : (z == 1 ? W1 : W2);
  float* Cm = (z == 0) ? C0 : (z == 1 ? C1 : C2);
  const int n0 = blockIdx.x * 128;
  const int m0 = blockIdx.y * 128;
  const int tid = threadIdx.x;
  const int tx = tid & 15, ty = tid >> 4;

  __shared__ float As[32][132];
  __shared__ float Bs[32][132];

  float acc[8][8];
#pragma unroll
  for (int i = 0; i < 8; ++i)
#pragma unroll
    for (int j = 0; j < 8; ++j) acc[i][j] = 0.f;

  for (int k0 = 0; k0 < 512; k0 += 32) {
    {
      const int c4 = tid & 7, r = tid >> 3;
#pragma unroll
      for (int p = 0; p < 128; p += 32) {
        float4 av = *(const float4*)&A[(size_t)(m0 + r + p) * 512 + k0 + c4 * 4];
        As[c4 * 4 + 0][r + p] = av.x;
        As[c4 * 4 + 1][r + p] = av.y;
        As[c4 * 4 + 2][r + p] = av.z;
        As[c4 * 4 + 3][r + p] = av.w;
      }
      const int j4 = tid & 31, rb = tid >> 5;
#pragma unroll
      for (int p = 0; p < 32; p += 8) {
        *(float4*)&Bs[rb + p][j4 * 4] =
            *(const float4*)&Wm[(size_t)(k0 + rb + p) * 512 + n0 + j4 * 4];
      }
    }
    __syncthreads();
#pragma unroll
    for (int kk = 0; kk < 32; ++kk) {
      float4 a0 = *(const float4*)&As[kk][ty * 8];
      float4 a1 = *(const float4*)&As[kk][ty * 8 + 4];
      float4 b0 = *(const float4*)&Bs[kk][tx * 8];
      float4 b1 = *(const float4*)&Bs[kk][tx * 8 + 4];
      float av[8] = {a0.x, a0.y, a0.z, a0.w, a1.x, a1.y, a1.z, a1.w};
      float bv[8] = {b0.x, b0.y, b0.z, b0.w, b1.x, b1.y, b1.z, b1.w};
#pragma unroll
      for (int i = 0; i < 8; ++i)
#pragma unroll
        for (int j = 0; j < 8; ++j) acc[i][j] += av[i] * bv[j];
    }
    __syncthreads();
  }
#pragma unroll
  for (int i = 0; i < 8; ++i) {
    size_t row = (size_t)(m0 + ty * 8 + i);
    float4 o0 = make_float4(acc[i][0], acc[i][1], acc[i][2], acc[i][3]);
    float4 o1 = make_float4(acc[i][4], acc[i][5], acc[i][6], acc[i][7]);
    *(float4*)&Cm[row * 512 + n0 + tx * 8] = o0;
    *(float4*)&Cm[row * 512 + n0 + tx * 8 + 4] = o1;
  }
}

// ---------------------------------------------------------------------------
// Fused sparse attention (unchanged from round 3).
// ---------------------------------------------------------------------------
__global__ __launch_bounds__(256, 3) void attn_kernel(
    const float* q,
    const float* __restrict__ k,
    const float* __restrict__ v,
    const int* __restrict__ labels,
    const float* __restrict__ scores,
    float* __restrict__ attn_out,
    float* o)
{
  const int bx = blockIdx.x;
  const int c = bx >> 10;
  const int rblk = bx & 1023;
  const int h = rblk & 7;
  const int g = (rblk >> 3) & 31;
  const int b = rblk >> 8;
  const int r0 = c * CHUNK;
  const int tid = threadIdx.x;
  const int lane = tid & 63, wv = tid >> 6;

  __shared__ float att[CHUNK][WSZ + 4];
  __shared__ float ktile[64][DH + 4];
  __shared__ int klab[WSZ];
  __shared__ float kscr[WSZ];
  __shared__ int hist8[8];
  __shared__ int s_sk, s_ck;

  {
    int j = tid;
    int pos = g * GSZ + j;
    int tok = pos < NN ? pos : (2 * NN - 1 - pos);
    klab[j] = labels[b * NN + tok];
    kscr[j] = scores[b * NN + tok];
  }
  __syncthreads();

  if (tid < 8) {
    int cnt = 0;
    for (int i = 0; i < GSZ; ++i) cnt += (klab[i] == tid);
    hist8[tid] = cnt;
  }
  __syncthreads();
  if (tid == 0) {
    int bc = hist8[0];
    for (int l = 1; l < 8; ++l)
      if (hist8[l] > bc) bc = hist8[l];
    float purity = (float)bc * (1.0f / GSZ);
    double mean = 0.0;
    for (int i = 0; i < GSZ; ++i) mean += (double)kscr[i];
    mean *= (1.0 / GSZ);
    double var = 0.0;
    for (int i = 0; i < GSZ; ++i) {
      double d = (double)kscr[i] - mean;
      var += d * d;
    }
    var *= (1.0 / GSZ);
    float focus = 0.5f + 0.25f * purity - 0.25f * (float)var;
    focus = fminf(fmaxf(focus, 0.25f), 0.75f);
    int keep = (int)ceilf(focus * (float)WSZ);
    keep = min(max(keep, 1), WSZ);
    int ck = keep >> 3, rem = keep & 7;
    if (rem > 4 || (rem == 4 && (ck & 1))) ck++;
    if (ck < 1) ck = 1;
    int sk = keep - ck;
    if (sk < 1) sk = 1;
    s_sk = sk;
    s_ck = ck;
  }
  __syncthreads();
  const int same_keep = s_sk, cross_keep = s_ck;

  const int rp = tid >> 4, jx = tid & 15;
  const int dstage = tid & 63, rstage = tid >> 6;

  const float* q0p = q + (size_t)(b * NN + g * GSZ + r0 + rp) * DIMM + h * DH;
  const float* q1p = q0p + (size_t)16 * DIMM;

  for (int jt = 0; jt < 4; ++jt) {
#pragma unroll
    for (int p = 0; p < 64; p += 4) {
      int j = jt * 64 + rstage + p;
      int pos = g * GSZ + j;
      int tok = pos < NN ? pos : (2 * NN - 1 - pos);
      ktile[rstage + p][dstage] = k[(size_t)(b * NN + tok) * DIMM + h * DH + dstage];
    }
    __syncthreads();
    float acc0[4] = {0.f, 0.f, 0.f, 0.f}, acc1[4] = {0.f, 0.f, 0.f, 0.f};
#pragma unroll
    for (int dd = 0; dd < DH; dd += 4) {
      float4 q0 = *(const float4*)(q0p + dd);
      float4 q1 = *(const float4*)(q1p + dd);
#pragma unroll
      for (int jj = 0; jj < 4; ++jj) {
        float4 kv = *(const float4*)&ktile[jx + 16 * jj][dd];
        acc0[jj] += q0.x * kv.x + q0.y * kv.y + q0.z * kv.z + q0.w * kv.w;
        acc1[jj] += q1.x * kv.x + q1.y * kv.y + q1.z * kv.z + q1.w * kv.w;
      }
    }
#pragma unroll
    for (int jj = 0; jj < 4; ++jj) {
      att[rp][jt * 64 + jx + 16 * jj] = acc0[jj] * 0.125f;
      att[rp + 16][jt * 64 + jx + 16 * jj] = acc1[jj] * 0.125f;
    }
    __syncthreads();
  }

  {
    int kl0[4];
    float ks0[4];
#pragma unroll
    for (int m = 0; m < 4; ++m) {
      kl0[m] = klab[lane + 64 * m];
      ks0[m] = kscr[lane + 64 * m];
    }
    for (int s = 0; s < 8; ++s) {
      const int rr = wv * 8 + s;
      const int qL = klab[r0 + rr];
      const float qS = kscr[r0 + rr];
      float a[4];
      float mx = -INFINITY;
#pragma unroll
      for (int m = 0; m < 4; ++m) {
        a[m] = att[rr][lane + 64 * m];
        mx = fmaxf(mx, a[m]);
      }
#pragma unroll
      for (int off = 32; off > 0; off >>= 1) mx = fmaxf(mx, __shfl_xor(mx, off));
      unsigned fs[4], fc[4];
      bool cand[4];
#pragma unroll
      for (int m = 0; m < 4; ++m) {
        a[m] = expf(a[m] - mx);
        cand[m] = (kl0[m] == qL);
        fs[m] = cand[m] ? __float_as_uint(a[m]) : 0u;
        fc[m] = __float_as_uint(a[m] * (qS * ks0[m]));
      }
      unsigned ts = 0, tc = 0;
      for (int bit = 29; bit >= 0; --bit) {
        unsigned cs = ts | (1u << bit), cc = tc | (1u << bit);
        int ns = 0, nc = 0;
#pragma unroll
        for (int m = 0; m < 4; ++m) {
          ns += __popcll(__ballot(fs[m] >= cs));
          nc += __popcll(__ballot(fc[m] >= cc));
        }
        if (ns >= same_keep) ts = cs;
        if (nc >= cross_keep) tc = cc;
      }
      unsigned long long beqs[4], beqc[4];
      int gts = 0, gtc = 0;
#pragma unroll
      for (int m = 0; m < 4; ++m) {
        gts += __popcll(__ballot(fs[m] > ts));
        gtc += __popcll(__ballot(fc[m] > tc));
        beqs[m] = __ballot(fs[m] == ts);
        beqc[m] = __ballot(fc[m] == tc);
      }
      const int rs = same_keep - gts, rc = cross_keep - gtc;
      float pv[4];
      float S = 0.f;
      int pres = 0, prec = 0;
#pragma unroll
      for (int m = 0; m < 4; ++m) {
        int mbs = __builtin_amdgcn_mbcnt_hi((unsigned)(beqs[m] >> 32),
                   __builtin_amdgcn_mbcnt_lo((unsigned)beqs[m], 0));
        int mbc = __builtin_amdgcn_mbcnt_hi((unsigned)(beqc[m] >> 32),
                   __builtin_amdgcn_mbcnt_lo((unsigned)beqc[m], 0));
        bool keep_s = cand[m] && ((fs[m] > ts) || ((fs[m] == ts) && (pres + mbs < rs)));
        bool keep_c = (!cand[m]) && ((fc[m] > tc) || ((fc[m] == tc) && (prec + mbc < rc)));
        pv[m] = (keep_s || keep_c) ? a[m] : 0.f;
        S += pv[m];
        pres += __popcll(beqs[m]);
        prec += __popcll(beqc[m]);
      }
#pragma unroll
      for (int off = 32; off > 0; off >>= 1) S += __shfl_xor(S, off);
      const float inv = 1.0f / S;
      size_t gb = ((((size_t)b * NGRP + g) * HH + h) * GSZ + (r0 + rr)) * WSZ + lane;
#pragma unroll
      for (int m = 0; m < 4; ++m) {
        float p = pv[m] * inv;
        att[rr][lane + 64 * m] = p;
        attn_out[gb + 64 * m] = p;
      }
    }
  }
  __syncthreads();

  const int dx = jx;
  float oa0[4] = {0.f, 0.f, 0.f, 0.f}, oa1[4] = {0.f, 0.f, 0.f, 0.f};
  for (int jt = 0; jt < 4; ++jt) {
#pragma unroll
    for (int p = 0; p < 64; p += 4) {
      int j = jt * 64 + rstage + p;
      int pos = g * GSZ + j;
      int tok = pos < NN ? pos : (2 * NN - 1 - pos);
      ktile[rstage + p][dstage] = v[(size_t)(b * NN + tok) * DIMM + h * DH + dstage];
    }
    __syncthreads();
#pragma unroll 4
    for (int jg = 0; jg < 16; ++jg) {
      float4 p0 = *(const float4*)&att[rp][jt * 64 + jg * 4];
      float4 p1 = *(const float4*)&att[rp + 16][jt * 64 + jg * 4];
      float4 v0 = *(const float4*)&ktile[jg * 4 + 0][dx * 4];
      float4 v1 = *(const float4*)&ktile[jg * 4 + 1][dx * 4];
      float4 v2 = *(const float4*)&ktile[jg * 4 + 2][dx * 4];
      float4 v3 = *(const float4*)&ktile[jg * 4 + 3][dx * 4];
      oa0[0] += p0.x * v0.x + p0.y * v1.x + p0.z * v2.x + p0.w * v3.x;
      oa0[1] += p0.x * v0.y + p0.y * v1.y + p0.z * v2.y + p0.w * v3.y;
      oa0[2] += p0.x * v0.z + p0.y * v1.z + p0.z * v2.z + p0.w * v3.z;
      oa0[3] += p0.x * v0.w + p0.y * v1.w + p0.z * v2.w + p0.w * v3.w;
      oa1[0] += p1.x * v0.x + p1.y * v1.x + p1.z * v2.x + p1.w * v3.x;
      oa1[1] += p1.x * v0.y + p1.y * v1.y + p1.z * v2.y + p1.w * v3.y;
      oa1[2] += p1.x * v0.z + p1.y * v1.z + p1.z * v2.z + p1.w * v3.z;
      oa1[3] += p1.x * v0.w + p1.y * v1.w + p1.z * v2.w + p1.w * v3.w;
    }
    __syncthreads();
  }
  {
    size_t ob0 = (size_t)(b * NN + g * GSZ + r0 + rp) * DIMM + h * DH + dx * 4;
    *(float4*)&o[ob0] = make_float4(oa0[0], oa0[1], oa0[2], oa0[3]);
    *(float4*)&o[ob0 + (size_t)16 * DIMM] = make_float4(oa1[0], oa1[1], oa1[2], oa1[3]);
  }
}

// ---------------------------------------------------------------------------
extern "C" void kernel_launch(void* const* d_in, const int* in_sizes, int n_in,
                              void* d_out, int out_size, void* d_ws, size_t ws_size,
                              hipStream_t stream) {
  const float* x      = (const float*)d_in[0];
  const int*   labels = (const int*)d_in[1];
  const float* scores = (const float*)d_in[2];
  const float* Wq     = (const float*)d_in[3];
  const float* Wk     = (const float*)d_in[4];
  const float* Wv     = (const float*)d_in[5];
  const float* Wproj  = (const float*)d_in[6];

  float* out = (float*)d_out;                               // (B, N, DIM)
  float* attn_out = out + (size_t)BB * NN * DIMM;           // (B, ng, H, gs, ws)

  const size_t SZ = (size_t)BB * NN * DIMM;                 // 8388608 floats
  float* qb = (float*)d_ws;
  float* kb = qb + SZ;
  float* vb = kb + SZ;

  // bf16 plane region after the 3 fp32 buffers
  unsigned short* xp    = (unsigned short*)((char*)d_ws + 3 * SZ * 4);
  unsigned short* wqkv  = xp + 3 * (size_t)MK;              // 9 planes (3 z x 3)
  unsigned short* wpp   = wqkv + 9 * (size_t)WK;            // 2 planes
  const size_t required = 3 * SZ * 4 +
                          (3 * (size_t)MK + 9 * (size_t)WK + 2 * (size_t)WK) * 2;

  if (ws_size >= required) {
    split_planes<<<dim3(MK / 1024), 256, 0, stream>>>(x, xp, 3);
    split_w<<<dim3(4 * WK / 256), 256, 0, stream>>>(Wq, Wk, Wv, Wproj, wqkv, wpp);
    // q, k, v: 6-term (fp32-exact) split GEMM; C = qb + z*SZ
    mfma_gemm<3, 6><<<dim3(4, 128, 3), 256, 0, stream>>>(xp, wqkv, qb);
    attn_kernel<<<dim3(BB * NGRP * HH * 4), 256, 0, stream>>>(qb, kb, vb, labels,
                                                              scores, attn_out, qb);
    // o (in qb) -> 2 planes (reuse xp region), then 3-term proj GEMM
    split_planes<<<dim3(MK / 1024), 256, 0, stream>>>(qb, xp, 2);
    mfma_gemm<2, 3><<<dim3(4, 128, 1), 256, 0, stream>>>(xp, wpp, out);
  } else {
    gemm512<<<dim3(4, 128, 3), 256, 0, stream>>>(x, Wq, Wk, Wv, qb, kb, vb);
    attn_kernel<<<dim3(BB * NGRP * HH * 4), 256, 0, stream>>>(qb, kb, vb, labels,
                                                              scores, attn_out, qb);
    gemm512<<<dim3(4, 128, 1), 256, 0, stream>>>(qb, Wproj, Wproj, Wproj, out, out, out);
  }
}

// Round 5
// 814.025 us; speedup vs baseline: 3.9855x; 1.1872x over previous
//
#include <hip/hip_runtime.h>

#define BB 4
#define NN 4096
#define DIMM 512
#define HH 8
#define DH 64
#define GSZ 128
#define NGRP 32
#define WSZ 256
#define CHUNK 32

#define MK 8388608u     // 16384*512 elements (x / q / k / v / o planes)
#define WK 262144u      // 512*512

typedef short short8 __attribute__((ext_vector_type(8)));
typedef float f32x4 __attribute__((ext_vector_type(4)));

__device__ inline unsigned short bf16rne(float f) {
  unsigned u = __float_as_uint(f);
  unsigned r = u + 0x7FFFu + ((u >> 16) & 1u);
  return (unsigned short)(r >> 16);
}
__device__ inline float bf16tof(unsigned short h) {
  return __uint_as_float(((unsigned)h) << 16);
}

// ---------------------------------------------------------------------------
// split_planes: fp32 -> 2 or 3 bf16 planes (hi, mid[, lo]); exact residual split
// ---------------------------------------------------------------------------
__global__ __launch_bounds__(256) void split_planes(
    const float* __restrict__ X, unsigned short* __restrict__ P, int np)
{
  unsigned idx = (blockIdx.x * 256u + threadIdx.x) * 4u;
  float4 xv = *(const float4*)&X[idx];
  float xs[4] = {xv.x, xv.y, xv.z, xv.w};
  ushort4 hv, mv, lv;
  unsigned short* hp = (unsigned short*)&hv;
  unsigned short* mp = (unsigned short*)&mv;
  unsigned short* lp = (unsigned short*)&lv;
#pragma unroll
  for (int i = 0; i < 4; ++i) {
    unsigned short h = bf16rne(xs[i]);
    float r1 = xs[i] - bf16tof(h);
    unsigned short m = bf16rne(r1);
    float r2 = r1 - bf16tof(m);
    hp[i] = h;
    mp[i] = m;
    lp[i] = bf16rne(r2);
  }
  *(ushort4*)&P[idx] = hv;
  *(ushort4*)&P[MK + idx] = mv;
  if (np == 3) *(ushort4*)&P[2u * MK + idx] = lv;
}

// ---------------------------------------------------------------------------
// split_w: weights -> transposed (N x K) bf16 planes.
// ---------------------------------------------------------------------------
__global__ __launch_bounds__(256) void split_w(
    const float* __restrict__ Wq, const float* __restrict__ Wk,
    const float* __restrict__ Wv, const float* __restrict__ Wpj,
    unsigned short* __restrict__ wqkv, unsigned short* __restrict__ wproj)
{
  unsigned e = blockIdx.x * 256u + threadIdx.x;     // over 4 * 2^18
  int mz = e >> 18;
  unsigned rem = e & (WK - 1u);
  unsigned kk = rem >> 9, n = rem & 511u;
  const float* src = (mz == 0) ? Wq : (mz == 1) ? Wk : (mz == 2) ? Wv : Wpj;
  float w = src[kk * 512u + n];
  unsigned short h = bf16rne(w);
  float r1 = w - bf16tof(h);
  unsigned short m = bf16rne(r1);
  float r2 = r1 - bf16tof(m);
  unsigned short l = bf16rne(r2);
  unsigned o = n * 512u + kk;
  if (mz < 3) {
    unsigned short* base = wqkv + (unsigned)mz * 3u * WK;
    base[o] = h;
    base[WK + o] = m;
    base[2u * WK + o] = l;
  } else {
    wproj[o] = h;
    wproj[WK + o] = m;
  }
}

// ---------------------------------------------------------------------------
// mfma_gemm: C[z] = A(16384x512) @ W[z](512x512) via split-bf16 MFMA.
// ---------------------------------------------------------------------------
template <int NP, int NT>
__global__ __launch_bounds__(256) void mfma_gemm(
    const unsigned short* __restrict__ Ap,   // NP planes, plane stride MK
    const unsigned short* __restrict__ Wp,   // [z][NP][n][k], plane stride WK
    float* __restrict__ C)                   // + z * 8388608
{
  constexpr int ta[6] = {0, 0, 1, 1, 0, 2};
  constexpr int tw[6] = {0, 1, 0, 1, 2, 0};
  const int z = blockIdx.z;
  const int n0 = blockIdx.x * 128;
  const int m0 = blockIdx.y * 128;
  const int tid = threadIdx.x;
  const int lane = tid & 63, wv = tid >> 6;
  const int wm = (wv >> 1) * 64, wn = (wv & 1) * 64;
  const int lm = lane & 15, lk = (lane >> 4) * 8;

  __shared__ unsigned short As[NP * 128 * 40];   // stride 40 bf16 = 80 B
  __shared__ unsigned short Ws[NP * 128 * 40];

  f32x4 acc[4][4];
#pragma unroll
  for (int i = 0; i < 4; ++i)
#pragma unroll
    for (int j = 0; j < 4; ++j) acc[i][j] = (f32x4){0.f, 0.f, 0.f, 0.f};

  const unsigned short* Wz = Wp + (size_t)z * NP * WK;

  for (int k0 = 0; k0 < 512; k0 += 32) {
#pragma unroll
    for (int i = 0; i < NP * 2; ++i) {
      int idx = i * 256 + tid;
      int p = idx >> 9, rem = idx & 511;
      int r = rem >> 2, cc = rem & 3;
      *(short8*)&As[p * 5120 + r * 40 + cc * 8] =
          *(const short8*)&Ap[(size_t)p * MK + (size_t)(m0 + r) * 512 + k0 + cc * 8];
      *(short8*)&Ws[p * 5120 + r * 40 + cc * 8] =
          *(const short8*)&Wz[(size_t)p * WK + (size_t)(n0 + r) * 512 + k0 + cc * 8];
    }
    __syncthreads();

    short8 a[NP][4];
#pragma unroll
    for (int p = 0; p < NP; ++p)
#pragma unroll
      for (int fm = 0; fm < 4; ++fm)
        a[p][fm] = *(const short8*)&As[p * 5120 + (wm + fm * 16 + lm) * 40 + lk];

#pragma unroll
    for (int fn = 0; fn < 4; ++fn) {
      short8 bf[NP];
#pragma unroll
      for (int p = 0; p < NP; ++p)
        bf[p] = *(const short8*)&Ws[p * 5120 + (wn + fn * 16 + lm) * 40 + lk];
#pragma unroll
      for (int fm = 0; fm < 4; ++fm) {
#pragma unroll
        for (int t = 0; t < NT; ++t)
          acc[fm][fn] = __builtin_amdgcn_mfma_f32_16x16x32_bf16(
              a[ta[t]][fm], bf[tw[t]], acc[fm][fn], 0, 0, 0);
      }
    }
    __syncthreads();
  }

  float* Cz = C + (size_t)z * 8388608u;
  const int rq = (lane >> 4) * 4;
#pragma unroll
  for (int fm = 0; fm < 4; ++fm)
#pragma unroll
    for (int fn = 0; fn < 4; ++fn) {
      int row = m0 + wm + fm * 16 + rq;
      int col = n0 + wn + fn * 16 + lm;
#pragma unroll
      for (int r = 0; r < 4; ++r)
        Cz[(size_t)(row + r) * 512 + col] = acc[fm][fn][r];
    }
}

// ---------------------------------------------------------------------------
// Fallback fp32 GEMM (used only if ws_size can't hold the bf16 planes).
// ---------------------------------------------------------------------------
__global__ __launch_bounds__(256) void gemm512(
    const float* __restrict__ A,
    const float* __restrict__ W0, const float* __restrict__ W1, const float* __restrict__ W2,
    float* __restrict__ C0, float* __restrict__ C1, float* __restrict__ C2)
{
  const int z = blockIdx.z;
  const float* Wm = (z == 0) ? W0 : (z == 1 ? W1 : W2);
  float* Cm = (z == 0) ? C0 : (z == 1 ? C1 : C2);
  const int n0 = blockIdx.x * 128;
  const int m0 = blockIdx.y * 128;
  const int tid = threadIdx.x;
  const int tx = tid & 15, ty = tid >> 4;

  __shared__ float As[32][132];
  __shared__ float Bs[32][132];

  float acc[8][8];
#pragma unroll
  for (int i = 0; i < 8; ++i)
#pragma unroll
    for (int j = 0; j < 8; ++j) acc[i][j] = 0.f;

  for (int k0 = 0; k0 < 512; k0 += 32) {
    {
      const int c4 = tid & 7, r = tid >> 3;
#pragma unroll
      for (int p = 0; p < 128; p += 32) {
        float4 av = *(const float4*)&A[(size_t)(m0 + r + p) * 512 + k0 + c4 * 4];
        As[c4 * 4 + 0][r + p] = av.x;
        As[c4 * 4 + 1][r + p] = av.y;
        As[c4 * 4 + 2][r + p] = av.z;
        As[c4 * 4 + 3][r + p] = av.w;
      }
      const int j4 = tid & 31, rb = tid >> 5;
#pragma unroll
      for (int p = 0; p < 32; p += 8) {
        *(float4*)&Bs[rb + p][j4 * 4] =
            *(const float4*)&Wm[(size_t)(k0 + rb + p) * 512 + n0 + j4 * 4];
      }
    }
    __syncthreads();
#pragma unroll
    for (int kk = 0; kk < 32; ++kk) {
      float4 a0 = *(const float4*)&As[kk][ty * 8];
      float4 a1 = *(const float4*)&As[kk][ty * 8 + 4];
      float4 b0 = *(const float4*)&Bs[kk][tx * 8];
      float4 b1 = *(const float4*)&Bs[kk][tx * 8 + 4];
      float av[8] = {a0.x, a0.y, a0.z, a0.w, a1.x, a1.y, a1.z, a1.w};
      float bv[8] = {b0.x, b0.y, b0.z, b0.w, b1.x, b1.y, b1.z, b1.w};
#pragma unroll
      for (int i = 0; i < 8; ++i)
#pragma unroll
        for (int j = 0; j < 8; ++j) acc[i][j] += av[i] * bv[j];
    }
    __syncthreads();
  }
#pragma unroll
  for (int i = 0; i < 8; ++i) {
    size_t row = (size_t)(m0 + ty * 8 + i);
    float4 o0 = make_float4(acc[i][0], acc[i][1], acc[i][2], acc[i][3]);
    float4 o1 = make_float4(acc[i][4], acc[i][5], acc[i][6], acc[i][7]);
    *(float4*)&Cm[row * 512 + n0 + tx * 8] = o0;
    *(float4*)&Cm[row * 512 + n0 + tx * 8 + 4] = o1;
  }
}

// ---------------------------------------------------------------------------
// Fused sparse attention. One block per (b, g, h, chunk-of-32-rows).
// v5: float4 k/v staging, pair-interleaved bisection (2 rows -> 4 threshold
// chains of ILP), parallel focus reduction, coalesced float4 attn_out pass.
// Ranking arithmetic is bit-identical to v4 (pure reordering).
// ---------------------------------------------------------------------------
__global__ __launch_bounds__(256, 3) void attn_kernel(
    const float* q,
    const float* __restrict__ k,
    const float* __restrict__ v,
    const int* __restrict__ labels,
    const float* __restrict__ scores,
    float* __restrict__ attn_out,
    float* o)
{
  const int bx = blockIdx.x;
  const int c = bx >> 10;
  const int rblk = bx & 1023;
  const int h = rblk & 7;
  const int g = (rblk >> 3) & 31;
  const int b = rblk >> 8;
  const int r0 = c * CHUNK;
  const int tid = threadIdx.x;
  const int lane = tid & 63, wv = tid >> 6;

  __shared__ float att[CHUNK][WSZ + 4];
  __shared__ float ktile[64][DH + 4];
  __shared__ int klab[WSZ];
  __shared__ float kscr[WSZ];
  __shared__ int hist8[8];
  __shared__ float s_var;
  __shared__ int s_sk, s_ck;

  {
    int j = tid;
    int pos = g * GSZ + j;
    int tok = pos < NN ? pos : (2 * NN - 1 - pos);
    klab[j] = labels[b * NN + tok];
    kscr[j] = scores[b * NN + tok];
  }
  if (tid < 8) hist8[tid] = 0;
  __syncthreads();

  // ---- focus inputs: histogram (LDS atomics) + mean/var (wave-0 reduce) ----
  if (tid < GSZ) atomicAdd(&hist8[klab[tid]], 1);
  if (wv == 0) {
    double x0 = (double)kscr[lane], x1 = (double)kscr[lane + 64];
    double s = x0 + x1;
#pragma unroll
    for (int off = 32; off > 0; off >>= 1) s += __shfl_xor(s, off);
    double mean = s * (1.0 / 128.0);
    double d0 = x0 - mean, d1 = x1 - mean;
    double vs = d0 * d0 + d1 * d1;
#pragma unroll
    for (int off = 32; off > 0; off >>= 1) vs += __shfl_xor(vs, off);
    if (lane == 0) s_var = (float)(vs * (1.0 / 128.0));
  }
  __syncthreads();
  if (tid == 0) {
    int bc = hist8[0];
    for (int l = 1; l < 8; ++l)
      if (hist8[l] > bc) bc = hist8[l];
    float purity = (float)bc * (1.0f / GSZ);
    float focus = 0.5f + 0.25f * purity - 0.25f * s_var;
    focus = fminf(fmaxf(focus, 0.25f), 0.75f);
    int keep = (int)ceilf(focus * (float)WSZ);
    keep = min(max(keep, 1), WSZ);
    int ck = keep >> 3, rem = keep & 7;          // round-half-even(keep/8)
    if (rem > 4 || (rem == 4 && (ck & 1))) ck++;
    if (ck < 1) ck = 1;
    int sk = keep - ck;
    if (sk < 1) sk = 1;
    s_sk = sk;
    s_ck = ck;
  }
  __syncthreads();
  const int same_keep = s_sk, cross_keep = s_ck;

  const int rp = tid >> 4, jx = tid & 15;
  const int srow = tid >> 4, sd4 = (tid & 15) * 4;   // float4 staging map

  const float* q0p = q + (size_t)(b * NN + g * GSZ + r0 + rp) * DIMM + h * DH;
  const float* q1p = q0p + (size_t)16 * DIMM;

  // ---- QK^T: logits into att (2 rows x 4 cols per thread) ----
  for (int jt = 0; jt < 4; ++jt) {
#pragma unroll
    for (int p = 0; p < 64; p += 16) {
      int j = jt * 64 + srow + p;
      int pos = g * GSZ + j;
      int tok = pos < NN ? pos : (2 * NN - 1 - pos);
      *(float4*)&ktile[srow + p][sd4] =
          *(const float4*)&k[(size_t)(b * NN + tok) * DIMM + h * DH + sd4];
    }
    __syncthreads();
    float acc0[4] = {0.f, 0.f, 0.f, 0.f}, acc1[4] = {0.f, 0.f, 0.f, 0.f};
#pragma unroll
    for (int dd = 0; dd < DH; dd += 4) {
      float4 q0 = *(const float4*)(q0p + dd);
      float4 q1 = *(const float4*)(q1p + dd);
#pragma unroll
      for (int jj = 0; jj < 4; ++jj) {
        float4 kv = *(const float4*)&ktile[jx + 16 * jj][dd];
        acc0[jj] += q0.x * kv.x + q0.y * kv.y + q0.z * kv.z + q0.w * kv.w;
        acc1[jj] += q1.x * kv.x + q1.y * kv.y + q1.z * kv.z + q1.w * kv.w;
      }
    }
#pragma unroll
    for (int jj = 0; jj < 4; ++jj) {
      att[rp][jt * 64 + jx + 16 * jj] = acc0[jj] * 0.125f;
      att[rp + 16][jt * 64 + jx + 16 * jj] = acc1[jj] * 0.125f;
    }
    __syncthreads();
  }

  // ---- fused softmax + exact top-k, 2 rows interleaved per wave-iteration --
  {
    int kl0[4];
    float ks0[4];
#pragma unroll
    for (int m = 0; m < 4; ++m) {
      kl0[m] = klab[lane + 64 * m];
      ks0[m] = kscr[lane + 64 * m];
    }
    for (int sp = 0; sp < 4; ++sp) {
      const int rA = wv * 8 + 2 * sp, rB = rA + 1;
      const int qLA = klab[r0 + rA], qLB = klab[r0 + rB];
      const float qSA = kscr[r0 + rA], qSB = kscr[r0 + rB];
      float aA[4], aB[4];
      float mxA = -INFINITY, mxB = -INFINITY;
#pragma unroll
      for (int m = 0; m < 4; ++m) {
        aA[m] = att[rA][lane + 64 * m];
        aB[m] = att[rB][lane + 64 * m];
        mxA = fmaxf(mxA, aA[m]);
        mxB = fmaxf(mxB, aB[m]);
      }
#pragma unroll
      for (int off = 32; off > 0; off >>= 1) {
        mxA = fmaxf(mxA, __shfl_xor(mxA, off));
        mxB = fmaxf(mxB, __shfl_xor(mxB, off));
      }
      unsigned fsA[4], fcA[4], fsB[4], fcB[4];
      bool cdA[4], cdB[4];
#pragma unroll
      for (int m = 0; m < 4; ++m) {
        aA[m] = expf(aA[m] - mxA);
        aB[m] = expf(aB[m] - mxB);
        cdA[m] = (kl0[m] == qLA);
        cdB[m] = (kl0[m] == qLB);
        fsA[m] = cdA[m] ? __float_as_uint(aA[m]) : 0u;
        fsB[m] = cdB[m] ? __float_as_uint(aB[m]) : 0u;
        fcA[m] = __float_as_uint(aA[m] * (qSA * ks0[m]));
        fcB[m] = __float_as_uint(aB[m] * (qSB * ks0[m]));
      }
      // 4 independent bisection chains (A/B x same/cross)
      unsigned tsA = 0, tcA = 0, tsB = 0, tcB = 0;
      for (int bit = 29; bit >= 0; --bit) {
        unsigned csA = tsA | (1u << bit), ccA = tcA | (1u << bit);
        unsigned csB = tsB | (1u << bit), ccB = tcB | (1u << bit);
        int nsA = 0, ncA = 0, nsB = 0, ncB = 0;
#pragma unroll
        for (int m = 0; m < 4; ++m) {
          nsA += __popcll(__ballot(fsA[m] >= csA));
          ncA += __popcll(__ballot(fcA[m] >= ccA));
          nsB += __popcll(__ballot(fsB[m] >= csB));
          ncB += __popcll(__ballot(fcB[m] >= ccB));
        }
        if (nsA >= same_keep) tsA = csA;
        if (ncA >= cross_keep) tcA = ccA;
        if (nsB >= same_keep) tsB = csB;
        if (ncB >= cross_keep) tcB = ccB;
      }
      // exact index tie-break among value-equals (smaller j wins)
#pragma unroll
      for (int rsel = 0; rsel < 2; ++rsel) {
        const int rr = rsel ? rB : rA;
        const unsigned ts = rsel ? tsB : tsA, tc = rsel ? tcB : tcA;
        unsigned* fs = rsel ? fsB : fsA;
        unsigned* fc = rsel ? fcB : fcA;
        float* a = rsel ? aB : aA;
        bool* cand = rsel ? cdB : cdA;
        unsigned long long beqs[4], beqc[4];
        int gts = 0, gtc = 0;
#pragma unroll
        for (int m = 0; m < 4; ++m) {
          gts += __popcll(__ballot(fs[m] > ts));
          gtc += __popcll(__ballot(fc[m] > tc));
          beqs[m] = __ballot(fs[m] == ts);
          beqc[m] = __ballot(fc[m] == tc);
        }
        const int rs = same_keep - gts, rc = cross_keep - gtc;
        float pv[4];
        float S = 0.f;
        int pres = 0, prec = 0;
#pragma unroll
        for (int m = 0; m < 4; ++m) {
          int mbs = __builtin_amdgcn_mbcnt_hi((unsigned)(beqs[m] >> 32),
                     __builtin_amdgcn_mbcnt_lo((unsigned)beqs[m], 0));
          int mbc = __builtin_amdgcn_mbcnt_hi((unsigned)(beqc[m] >> 32),
                     __builtin_amdgcn_mbcnt_lo((unsigned)beqc[m], 0));
          bool keep_s = cand[m] && ((fs[m] > ts) || ((fs[m] == ts) && (pres + mbs < rs)));
          bool keep_c = (!cand[m]) && ((fc[m] > tc) || ((fc[m] == tc) && (prec + mbc < rc)));
          pv[m] = (keep_s || keep_c) ? a[m] : 0.f;
          S += pv[m];
          pres += __popcll(beqs[m]);
          prec += __popcll(beqc[m]);
        }
#pragma unroll
        for (int off = 32; off > 0; off >>= 1) S += __shfl_xor(S, off);
        const float inv = 1.0f / S;
#pragma unroll
        for (int m = 0; m < 4; ++m) att[rr][lane + 64 * m] = pv[m] * inv;
      }
    }
  }
  __syncthreads();

  // ---- coalesced attn_out write: (b, g, h, gs, ws) as float4 ----
  {
    size_t base = ((((size_t)b * NGRP + g) * HH + h) * GSZ + r0) * WSZ;
#pragma unroll
    for (int it = 0; it < 8; ++it) {
      int idx = it * 256 + tid;
      int i = idx >> 6, j4 = (idx & 63) * 4;
      *(float4*)&attn_out[base + (size_t)i * WSZ + j4] = *(float4*)&att[i][j4];
    }
  }

  // ---- PV: o_chunk = p @ v_window (2 rows x 4 d per thread, j-blocked 4) ----
  const int dx = jx;
  float oa0[4] = {0.f, 0.f, 0.f, 0.f}, oa1[4] = {0.f, 0.f, 0.f, 0.f};
  for (int jt = 0; jt < 4; ++jt) {
#pragma unroll
    for (int p = 0; p < 64; p += 16) {
      int j = jt * 64 + srow + p;
      int pos = g * GSZ + j;
      int tok = pos < NN ? pos : (2 * NN - 1 - pos);
      *(float4*)&ktile[srow + p][sd4] =
          *(const float4*)&v[(size_t)(b * NN + tok) * DIMM + h * DH + sd4];
    }
    __syncthreads();
#pragma unroll 4
    for (int jg = 0; jg < 16; ++jg) {
      float4 p0 = *(const float4*)&att[rp][jt * 64 + jg * 4];
      float4 p1 = *(const float4*)&att[rp + 16][jt * 64 + jg * 4];
      float4 v0 = *(const float4*)&ktile[jg * 4 + 0][dx * 4];
      float4 v1 = *(const float4*)&ktile[jg * 4 + 1][dx * 4];
      float4 v2 = *(const float4*)&ktile[jg * 4 + 2][dx * 4];
      float4 v3 = *(const float4*)&ktile[jg * 4 + 3][dx * 4];
      oa0[0] += p0.x * v0.x + p0.y * v1.x + p0.z * v2.x + p0.w * v3.x;
      oa0[1] += p0.x * v0.y + p0.y * v1.y + p0.z * v2.y + p0.w * v3.y;
      oa0[2] += p0.x * v0.z + p0.y * v1.z + p0.z * v2.z + p0.w * v3.z;
      oa0[3] += p0.x * v0.w + p0.y * v1.w + p0.z * v2.w + p0.w * v3.w;
      oa1[0] += p1.x * v0.x + p1.y * v1.x + p1.z * v2.x + p1.w * v3.x;
      oa1[1] += p1.x * v0.y + p1.y * v1.y + p1.z * v2.y + p1.w * v3.y;
      oa1[2] += p1.x * v0.z + p1.y * v1.z + p1.z * v2.z + p1.w * v3.z;
      oa1[3] += p1.x * v0.w + p1.y * v1.w + p1.z * v2.w + p1.w * v3.w;
    }
    __syncthreads();
  }
  {
    size_t ob0 = (size_t)(b * NN + g * GSZ + r0 + rp) * DIMM + h * DH + dx * 4;
    *(float4*)&o[ob0] = make_float4(oa0[0], oa0[1], oa0[2], oa0[3]);
    *(float4*)&o[ob0 + (size_t)16 * DIMM] = make_float4(oa1[0], oa1[1], oa1[2], oa1[3]);
  }
}

// ---------------------------------------------------------------------------
extern "C" void kernel_launch(void* const* d_in, const int* in_sizes, int n_in,
                              void* d_out, int out_size, void* d_ws, size_t ws_size,
                              hipStream_t stream) {
  const float* x      = (const float*)d_in[0];
  const int*   labels = (const int*)d_in[1];
  const float* scores = (const float*)d_in[2];
  const float* Wq     = (const float*)d_in[3];
  const float* Wk     = (const float*)d_in[4];
  const float* Wv     = (const float*)d_in[5];
  const float* Wproj  = (const float*)d_in[6];

  float* out = (float*)d_out;                               // (B, N, DIM)
  float* attn_out = out + (size_t)BB * NN * DIMM;           // (B, ng, H, gs, ws)

  const size_t SZ = (size_t)BB * NN * DIMM;                 // 8388608 floats
  float* qb = (float*)d_ws;
  float* kb = qb + SZ;
  float* vb = kb + SZ;

  unsigned short* xp    = (unsigned short*)((char*)d_ws + 3 * SZ * 4);
  unsigned short* wqkv  = xp + 3 * (size_t)MK;              // 9 planes (3 z x 3)
  unsigned short* wpp   = wqkv + 9 * (size_t)WK;            // 2 planes
  const size_t required = 3 * SZ * 4 +
                          (3 * (size_t)MK + 9 * (size_t)WK + 2 * (size_t)WK) * 2;

  if (ws_size >= required) {
    split_planes<<<dim3(MK / 1024), 256, 0, stream>>>(x, xp, 3);
    split_w<<<dim3(4 * WK / 256), 256, 0, stream>>>(Wq, Wk, Wv, Wproj, wqkv, wpp);
    mfma_gemm<3, 6><<<dim3(4, 128, 3), 256, 0, stream>>>(xp, wqkv, qb);
    attn_kernel<<<dim3(BB * NGRP * HH * 4), 256, 0, stream>>>(qb, kb, vb, labels,
                                                              scores, attn_out, qb);
    split_planes<<<dim3(MK / 1024), 256, 0, stream>>>(qb, xp, 2);
    mfma_gemm<2, 3><<<dim3(4, 128, 1), 256, 0, stream>>>(xp, wpp, out);
  } else {
    gemm512<<<dim3(4, 128, 3), 256, 0, stream>>>(x, Wq, Wk, Wv, qb, kb, vb);
    attn_kernel<<<dim3(BB * NGRP * HH * 4), 256, 0, stream>>>(qb, kb, vb, labels,
                                                              scores, attn_out, qb);
    gemm512<<<dim3(4, 128, 1), 256, 0, stream>>>(qb, Wproj, Wproj, Wproj, out, out, out);
  }
}

// Round 8
// 810.960 us; speedup vs baseline: 4.0006x; 1.0038x over previous
//
#include <hip/hip_runtime.h>

#define BB 4
#define NN 4096
#define DIMM 512
#define HH 8
#define DH 64
#define GSZ 128
#define NGRP 32
#define WSZ 256
#define CHUNK 32

#define MK 8388608u     // 16384*512 elements (x / q / k / v / o planes)
#define WK 262144u      // 512*512

typedef short short8 __attribute__((ext_vector_type(8)));
typedef float f32x4 __attribute__((ext_vector_type(4)));

__device__ inline unsigned short bf16rne(float f) {
  unsigned u = __float_as_uint(f);
  unsigned r = u + 0x7FFFu + ((u >> 16) & 1u);
  return (unsigned short)(r >> 16);
}
__device__ inline float bf16tof(unsigned short h) {
  return __uint_as_float(((unsigned)h) << 16);
}

// ---------------------------------------------------------------------------
// split_planes: fp32 -> 3 bf16 planes (hi, mid, lo); exact residual split
// ---------------------------------------------------------------------------
__global__ __launch_bounds__(256) void split_planes(
    const float* __restrict__ X, unsigned short* __restrict__ P)
{
  unsigned idx = (blockIdx.x * 256u + threadIdx.x) * 4u;
  float4 xv = *(const float4*)&X[idx];
  float xs[4] = {xv.x, xv.y, xv.z, xv.w};
  ushort4 hv, mv, lv;
  unsigned short* hp = (unsigned short*)&hv;
  unsigned short* mp = (unsigned short*)&mv;
  unsigned short* lp = (unsigned short*)&lv;
#pragma unroll
  for (int i = 0; i < 4; ++i) {
    unsigned short h = bf16rne(xs[i]);
    float r1 = xs[i] - bf16tof(h);
    unsigned short m = bf16rne(r1);
    float r2 = r1 - bf16tof(m);
    hp[i] = h;
    mp[i] = m;
    lp[i] = bf16rne(r2);
  }
  *(ushort4*)&P[idx] = hv;
  *(ushort4*)&P[MK + idx] = mv;
  *(ushort4*)&P[2u * MK + idx] = lv;
}

// ---------------------------------------------------------------------------
// split_w: weights -> transposed (N x K) bf16 planes.
// ---------------------------------------------------------------------------
__global__ __launch_bounds__(256) void split_w(
    const float* __restrict__ Wq, const float* __restrict__ Wk,
    const float* __restrict__ Wv, const float* __restrict__ Wpj,
    unsigned short* __restrict__ wqkv, unsigned short* __restrict__ wproj)
{
  unsigned e = blockIdx.x * 256u + threadIdx.x;     // over 4 * 2^18
  int mz = e >> 18;
  unsigned rem = e & (WK - 1u);
  unsigned kk = rem >> 9, n = rem & 511u;
  const float* src = (mz == 0) ? Wq : (mz == 1) ? Wk : (mz == 2) ? Wv : Wpj;
  float w = src[kk * 512u + n];
  unsigned short h = bf16rne(w);
  float r1 = w - bf16tof(h);
  unsigned short m = bf16rne(r1);
  float r2 = r1 - bf16tof(m);
  unsigned short l = bf16rne(r2);
  unsigned o = n * 512u + kk;
  if (mz < 3) {
    unsigned short* base = wqkv + (unsigned)mz * 3u * WK;
    base[o] = h;
    base[WK + o] = m;
    base[2u * WK + o] = l;
  } else {
    wproj[o] = h;
    wproj[WK + o] = m;
  }
}

// ---------------------------------------------------------------------------
// mfma_gemm: C[z] = A(16384x512) @ W[z](512x512) via split-bf16 MFMA.
// fp32 output to C + z*8388608.
// ---------------------------------------------------------------------------
template <int NP, int NT>
__global__ __launch_bounds__(256) void mfma_gemm(
    const unsigned short* __restrict__ Ap,   // NP planes, plane stride MK
    const unsigned short* __restrict__ Wp,   // [z][NP][n][k], plane stride WK
    float* __restrict__ C)
{
  constexpr int ta[6] = {0, 0, 1, 1, 0, 2};
  constexpr int tw[6] = {0, 1, 0, 1, 2, 0};
  const int z = blockIdx.z;
  const int n0 = blockIdx.x * 128;
  const int m0 = blockIdx.y * 128;
  const int tid = threadIdx.x;
  const int lane = tid & 63, wv = tid >> 6;
  const int wm = (wv >> 1) * 64, wn = (wv & 1) * 64;
  const int lm = lane & 15, lk = (lane >> 4) * 8;

  __shared__ unsigned short As[NP * 128 * 40];   // stride 40 bf16 = 80 B
  __shared__ unsigned short Ws[NP * 128 * 40];

  f32x4 acc[4][4];
#pragma unroll
  for (int i = 0; i < 4; ++i)
#pragma unroll
    for (int j = 0; j < 4; ++j) acc[i][j] = (f32x4){0.f, 0.f, 0.f, 0.f};

  const unsigned short* Wz = Wp + (size_t)z * NP * WK;

  for (int k0 = 0; k0 < 512; k0 += 32) {
#pragma unroll
    for (int i = 0; i < NP * 2; ++i) {
      int idx = i * 256 + tid;
      int p = idx >> 9, rem = idx & 511;
      int r = rem >> 2, cc = rem & 3;
      *(short8*)&As[p * 5120 + r * 40 + cc * 8] =
          *(const short8*)&Ap[(size_t)p * MK + (size_t)(m0 + r) * 512 + k0 + cc * 8];
      *(short8*)&Ws[p * 5120 + r * 40 + cc * 8] =
          *(const short8*)&Wz[(size_t)p * WK + (size_t)(n0 + r) * 512 + k0 + cc * 8];
    }
    __syncthreads();

    short8 a[NP][4];
#pragma unroll
    for (int p = 0; p < NP; ++p)
#pragma unroll
      for (int fm = 0; fm < 4; ++fm)
        a[p][fm] = *(const short8*)&As[p * 5120 + (wm + fm * 16 + lm) * 40 + lk];

#pragma unroll
    for (int fn = 0; fn < 4; ++fn) {
      short8 bf[NP];
#pragma unroll
      for (int p = 0; p < NP; ++p)
        bf[p] = *(const short8*)&Ws[p * 5120 + (wn + fn * 16 + lm) * 40 + lk];
#pragma unroll
      for (int fm = 0; fm < 4; ++fm) {
#pragma unroll
        for (int t = 0; t < NT; ++t)
          acc[fm][fn] = __builtin_amdgcn_mfma_f32_16x16x32_bf16(
              a[ta[t]][fm], bf[tw[t]], acc[fm][fn], 0, 0, 0);
      }
    }
    __syncthreads();
  }

  const int rq = (lane >> 4) * 4;
  float* Cz = C + (size_t)z * 8388608u;
#pragma unroll
  for (int fm = 0; fm < 4; ++fm)
#pragma unroll
    for (int fn = 0; fn < 4; ++fn) {
      int row = m0 + wm + fm * 16 + rq;
      int col = n0 + wn + fn * 16 + lm;
#pragma unroll
      for (int r = 0; r < 4; ++r)
        Cz[(size_t)(row + r) * 512 + col] = acc[fm][fn][r];
    }
}

// ---------------------------------------------------------------------------
// Fallback fp32 GEMM (used only if ws_size can't hold the bf16 planes).
// ---------------------------------------------------------------------------
__global__ __launch_bounds__(256) void gemm512(
    const float* __restrict__ A,
    const float* __restrict__ W0, const float* __restrict__ W1, const float* __restrict__ W2,
    float* __restrict__ C0, float* __restrict__ C1, float* __restrict__ C2)
{
  const int z = blockIdx.z;
  const float* Wm = (z == 0) ? W0 : (z == 1 ? W1 : W2);
  float* Cm = (z == 0) ? C0 : (z == 1 ? C1 : C2);
  const int n0 = blockIdx.x * 128;
  const int m0 = blockIdx.y * 128;
  const int tid = threadIdx.x;
  const int tx = tid & 15, ty = tid >> 4;

  __shared__ float As[32][132];
  __shared__ float Bs[32][132];

  float acc[8][8];
#pragma unroll
  for (int i = 0; i < 8; ++i)
#pragma unroll
    for (int j = 0; j < 8; ++j) acc[i][j] = 0.f;

  for (int k0 = 0; k0 < 512; k0 += 32) {
    {
      const int c4 = tid & 7, r = tid >> 3;
#pragma unroll
      for (int p = 0; p < 128; p += 32) {
        float4 av = *(const float4*)&A[(size_t)(m0 + r + p) * 512 + k0 + c4 * 4];
        As[c4 * 4 + 0][r + p] = av.x;
        As[c4 * 4 + 1][r + p] = av.y;
        As[c4 * 4 + 2][r + p] = av.z;
        As[c4 * 4 + 3][r + p] = av.w;
      }
      const int j4 = tid & 31, rb = tid >> 5;
#pragma unroll
      for (int p = 0; p < 32; p += 8) {
        *(float4*)&Bs[rb + p][j4 * 4] =
            *(const float4*)&Wm[(size_t)(k0 + rb + p) * 512 + n0 + j4 * 4];
      }
    }
    __syncthreads();
#pragma unroll
    for (int kk = 0; kk < 32; ++kk) {
      float4 a0 = *(const float4*)&As[kk][ty * 8];
      float4 a1 = *(const float4*)&As[kk][ty * 8 + 4];
      float4 b0 = *(const float4*)&Bs[kk][tx * 8];
      float4 b1 = *(const float4*)&Bs[kk][tx * 8 + 4];
      float av[8] = {a0.x, a0.y, a0.z, a0.w, a1.x, a1.y, a1.z, a1.w};
      float bv[8] = {b0.x, b0.y, b0.z, b0.w, b1.x, b1.y, b1.z, b1.w};
#pragma unroll
      for (int i = 0; i < 8; ++i)
#pragma unroll
        for (int j = 0; j < 8; ++j) acc[i][j] += av[i] * bv[j];
    }
    __syncthreads();
  }
#pragma unroll
  for (int i = 0; i < 8; ++i) {
    size_t row = (size_t)(m0 + ty * 8 + i);
    float4 o0 = make_float4(acc[i][0], acc[i][1], acc[i][2], acc[i][3]);
    float4 o1 = make_float4(acc[i][4], acc[i][5], acc[i][6], acc[i][7]);
    *(float4*)&Cm[row * 512 + n0 + tx * 8] = o0;
    *(float4*)&Cm[row * 512 + n0 + tx * 8 + 4] = o1;
  }
}

// ---------------------------------------------------------------------------
// Shared device code for the focus/keep computation + rank phase.
// ---------------------------------------------------------------------------
__device__ __forceinline__ void focus_keep(
    const int* klab, const float* kscr, int* hist8, float* s_var,
    int* s_sk, int* s_ck, int tid, int lane, int wv)
{
  if (tid < GSZ) atomicAdd(&hist8[klab[tid]], 1);
  if (wv == 0) {
    double x0 = (double)kscr[lane], x1 = (double)kscr[lane + 64];
    double s = x0 + x1;
#pragma unroll
    for (int off = 32; off > 0; off >>= 1) s += __shfl_xor(s, off);
    double mean = s * (1.0 / 128.0);
    double d0 = x0 - mean, d1 = x1 - mean;
    double vs = d0 * d0 + d1 * d1;
#pragma unroll
    for (int off = 32; off > 0; off >>= 1) vs += __shfl_xor(vs, off);
    if (lane == 0) *s_var = (float)(vs * (1.0 / 128.0));
  }
  __syncthreads();
  if (tid == 0) {
    int bc = hist8[0];
    for (int l = 1; l < 8; ++l)
      if (hist8[l] > bc) bc = hist8[l];
    float purity = (float)bc * (1.0f / GSZ);
    float focus = 0.5f + 0.25f * purity - 0.25f * (*s_var);
    focus = fminf(fmaxf(focus, 0.25f), 0.75f);
    int keep = (int)ceilf(focus * (float)WSZ);
    keep = min(max(keep, 1), WSZ);
    int ck = keep >> 3, rem = keep & 7;          // round-half-even(keep/8)
    if (rem > 4 || (rem == 4 && (ck & 1))) ck++;
    if (ck < 1) ck = 1;
    int sk = keep - ck;
    if (sk < 1) sk = 1;
    *s_sk = sk;
    *s_ck = ck;
  }
  __syncthreads();
}

__device__ __forceinline__ void rank_rows(
    float att[CHUNK][WSZ + 4], const int* klab, const float* kscr,
    int r0, int same_keep, int cross_keep, int lane, int wv)
{
  int kl0[4];
  float ks0[4];
#pragma unroll
  for (int m = 0; m < 4; ++m) {
    kl0[m] = klab[lane + 64 * m];
    ks0[m] = kscr[lane + 64 * m];
  }
  for (int sp = 0; sp < 4; ++sp) {
    const int rA = wv * 8 + 2 * sp, rB = rA + 1;
    const int qLA = klab[r0 + rA], qLB = klab[r0 + rB];
    const float qSA = kscr[r0 + rA], qSB = kscr[r0 + rB];
    float aA[4], aB[4];
    float mxA = -INFINITY, mxB = -INFINITY;
#pragma unroll
    for (int m = 0; m < 4; ++m) {
      aA[m] = att[rA][lane + 64 * m];
      aB[m] = att[rB][lane + 64 * m];
      mxA = fmaxf(mxA, aA[m]);
      mxB = fmaxf(mxB, aB[m]);
    }
#pragma unroll
    for (int off = 32; off > 0; off >>= 1) {
      mxA = fmaxf(mxA, __shfl_xor(mxA, off));
      mxB = fmaxf(mxB, __shfl_xor(mxB, off));
    }
    unsigned fsA[4], fcA[4], fsB[4], fcB[4];
    bool cdA[4], cdB[4];
#pragma unroll
    for (int m = 0; m < 4; ++m) {
      aA[m] = expf(aA[m] - mxA);
      aB[m] = expf(aB[m] - mxB);
      cdA[m] = (kl0[m] == qLA);
      cdB[m] = (kl0[m] == qLB);
      fsA[m] = cdA[m] ? __float_as_uint(aA[m]) : 0u;
      fsB[m] = cdB[m] ? __float_as_uint(aB[m]) : 0u;
      fcA[m] = __float_as_uint(aA[m] * (qSA * ks0[m]));
      fcB[m] = __float_as_uint(aB[m] * (qSB * ks0[m]));
    }
    unsigned tsA = 0, tcA = 0, tsB = 0, tcB = 0;
    for (int bit = 29; bit >= 0; --bit) {
      unsigned csA = tsA | (1u << bit), ccA = tcA | (1u << bit);
      unsigned csB = tsB | (1u << bit), ccB = tcB | (1u << bit);
      int nsA = 0, ncA = 0, nsB = 0, ncB = 0;
#pragma unroll
      for (int m = 0; m < 4; ++m) {
        nsA += __popcll(__ballot(fsA[m] >= csA));
        ncA += __popcll(__ballot(fcA[m] >= ccA));
        nsB += __popcll(__ballot(fsB[m] >= csB));
        ncB += __popcll(__ballot(fcB[m] >= ccB));
      }
      if (nsA >= same_keep) tsA = csA;
      if (ncA >= cross_keep) tcA = ccA;
      if (nsB >= same_keep) tsB = csB;
      if (ncB >= cross_keep) tcB = ccB;
    }
#pragma unroll
    for (int rsel = 0; rsel < 2; ++rsel) {
      const int rr = rsel ? rB : rA;
      const unsigned ts = rsel ? tsB : tsA, tc = rsel ? tcB : tcA;
      unsigned* fs = rsel ? fsB : fsA;
      unsigned* fc = rsel ? fcB : fcA;
      float* a = rsel ? aB : aA;
      bool* cand = rsel ? cdB : cdA;
      unsigned long long beqs[4], beqc[4];
      int gts = 0, gtc = 0;
#pragma unroll
      for (int m = 0; m < 4; ++m) {
        gts += __popcll(__ballot(fs[m] > ts));
        gtc += __popcll(__ballot(fc[m] > tc));
        beqs[m] = __ballot(fs[m] == ts);
        beqc[m] = __ballot(fc[m] == tc);
      }
      const int rs = same_keep - gts, rc = cross_keep - gtc;
      float pv[4];
      float S = 0.f;
      int pres = 0, prec = 0;
#pragma unroll
      for (int m = 0; m < 4; ++m) {
        int mbs = __builtin_amdgcn_mbcnt_hi((unsigned)(beqs[m] >> 32),
                   __builtin_amdgcn_mbcnt_lo((unsigned)beqs[m], 0));
        int mbc = __builtin_amdgcn_mbcnt_hi((unsigned)(beqc[m] >> 32),
                   __builtin_amdgcn_mbcnt_lo((unsigned)beqc[m], 0));
        bool keep_s = cand[m] && ((fs[m] > ts) || ((fs[m] == ts) && (pres + mbs < rs)));
        bool keep_c = (!cand[m]) && ((fc[m] > tc) || ((fc[m] == tc) && (prec + mbc < rc)));
        pv[m] = (keep_s || keep_c) ? a[m] : 0.f;
        S += pv[m];
        pres += __popcll(beqs[m]);
        prec += __popcll(beqc[m]);
      }
#pragma unroll
      for (int off = 32; off > 0; off >>= 1) S += __shfl_xor(S, off);
      const float inv = 1.0f / S;
#pragma unroll
      for (int m = 0; m < 4; ++m) att[rr][lane + 64 * m] = pv[m] * inv;
    }
  }
}

// ---------------------------------------------------------------------------
// attn v8: R5-exact selection path (fp32 q/k, VALU QK, identical rank).
// OMODE 0: write fp32 o (aliases q — fallback path).
// OMODE 1: write o as 2 bf16 planes (hi/mid) feeding the proj MFMA GEMM.
// ---------------------------------------------------------------------------
template <int OMODE>
__global__ __launch_bounds__(256, 3) void attn_f32(
    const float* q, const float* __restrict__ k, const float* __restrict__ v,
    const int* __restrict__ labels, const float* __restrict__ scores,
    float* __restrict__ attn_out, float* o, unsigned short* __restrict__ opl)
{
  const int bx = blockIdx.x;
  const int c = bx >> 10;
  const int rblk = bx & 1023;
  const int h = rblk & 7;
  const int g = (rblk >> 3) & 31;
  const int b = rblk >> 8;
  const int r0 = c * CHUNK;
  const int tid = threadIdx.x;
  const int lane = tid & 63, wv = tid >> 6;

  __shared__ float att[CHUNK][WSZ + 4];
  __shared__ float ktile[64][DH + 4];
  __shared__ int klab[WSZ];
  __shared__ float kscr[WSZ];
  __shared__ int hist8[8];
  __shared__ float s_var;
  __shared__ int s_sk, s_ck;

  {
    int j = tid;
    int pos = g * GSZ + j;
    int tok = pos < NN ? pos : (2 * NN - 1 - pos);
    klab[j] = labels[b * NN + tok];
    kscr[j] = scores[b * NN + tok];
  }
  if (tid < 8) hist8[tid] = 0;
  __syncthreads();
  focus_keep(klab, kscr, hist8, &s_var, &s_sk, &s_ck, tid, lane, wv);
  const int same_keep = s_sk, cross_keep = s_ck;

  const int rp = tid >> 4, jx = tid & 15;
  const int srow = tid >> 4, sd4 = (tid & 15) * 4;
  const float* q0p = q + (size_t)(b * NN + g * GSZ + r0 + rp) * DIMM + h * DH;
  const float* q1p = q0p + (size_t)16 * DIMM;

  // ---- QK^T: fp32 VALU, bit-identical to the round-5 passing kernel ----
  for (int jt = 0; jt < 4; ++jt) {
#pragma unroll
    for (int p = 0; p < 64; p += 16) {
      int j = jt * 64 + srow + p;
      int pos = g * GSZ + j;
      int tok = pos < NN ? pos : (2 * NN - 1 - pos);
      *(float4*)&ktile[srow + p][sd4] =
          *(const float4*)&k[(size_t)(b * NN + tok) * DIMM + h * DH + sd4];
    }
    __syncthreads();
    float acc0[4] = {0.f, 0.f, 0.f, 0.f}, acc1[4] = {0.f, 0.f, 0.f, 0.f};
#pragma unroll
    for (int dd = 0; dd < DH; dd += 4) {
      float4 q0 = *(const float4*)(q0p + dd);
      float4 q1 = *(const float4*)(q1p + dd);
#pragma unroll
      for (int jj = 0; jj < 4; ++jj) {
        float4 kv = *(const float4*)&ktile[jx + 16 * jj][dd];
        acc0[jj] += q0.x * kv.x + q0.y * kv.y + q0.z * kv.z + q0.w * kv.w;
        acc1[jj] += q1.x * kv.x + q1.y * kv.y + q1.z * kv.z + q1.w * kv.w;
      }
    }
#pragma unroll
    for (int jj = 0; jj < 4; ++jj) {
      att[rp][jt * 64 + jx + 16 * jj] = acc0[jj] * 0.125f;
      att[rp + 16][jt * 64 + jx + 16 * jj] = acc1[jj] * 0.125f;
    }
    __syncthreads();
  }

  rank_rows(att, klab, kscr, r0, same_keep, cross_keep, lane, wv);
  __syncthreads();

  // ---- coalesced attn_out write ----
  {
    size_t base = ((((size_t)b * NGRP + g) * HH + h) * GSZ + r0) * WSZ;
#pragma unroll
    for (int it = 0; it < 8; ++it) {
      int idx = it * 256 + tid;
      int i = idx >> 6, j4 = (idx & 63) * 4;
      *(float4*)&attn_out[base + (size_t)i * WSZ + j4] = *(float4*)&att[i][j4];
    }
  }

  // ---- PV: o_chunk = p @ v_window ----
  const int dx = jx;
  float oa0[4] = {0.f, 0.f, 0.f, 0.f}, oa1[4] = {0.f, 0.f, 0.f, 0.f};
  for (int jt = 0; jt < 4; ++jt) {
#pragma unroll
    for (int p = 0; p < 64; p += 16) {
      int j = jt * 64 + srow + p;
      int pos = g * GSZ + j;
      int tok = pos < NN ? pos : (2 * NN - 1 - pos);
      *(float4*)&ktile[srow + p][sd4] =
          *(const float4*)&v[(size_t)(b * NN + tok) * DIMM + h * DH + sd4];
    }
    __syncthreads();
#pragma unroll 4
    for (int jg = 0; jg < 16; ++jg) {
      float4 p0 = *(const float4*)&att[rp][jt * 64 + jg * 4];
      float4 p1 = *(const float4*)&att[rp + 16][jt * 64 + jg * 4];
      float4 v0 = *(const float4*)&ktile[jg * 4 + 0][dx * 4];
      float4 v1 = *(const float4*)&ktile[jg * 4 + 1][dx * 4];
      float4 v2 = *(const float4*)&ktile[jg * 4 + 2][dx * 4];
      float4 v3 = *(const float4*)&ktile[jg * 4 + 3][dx * 4];
      oa0[0] += p0.x * v0.x + p0.y * v1.x + p0.z * v2.x + p0.w * v3.x;
      oa0[1] += p0.x * v0.y + p0.y * v1.y + p0.z * v2.y + p0.w * v3.y;
      oa0[2] += p0.x * v0.z + p0.y * v1.z + p0.z * v2.z + p0.w * v3.z;
      oa0[3] += p0.x * v0.w + p0.y * v1.w + p0.z * v2.w + p0.w * v3.w;
      oa1[0] += p1.x * v0.x + p1.y * v1.x + p1.z * v2.x + p1.w * v3.x;
      oa1[1] += p1.x * v0.y + p1.y * v1.y + p1.z * v2.y + p1.w * v3.y;
      oa1[2] += p1.x * v0.z + p1.y * v1.z + p1.z * v2.z + p1.w * v3.z;
      oa1[3] += p1.x * v0.w + p1.y * v1.w + p1.z * v2.w + p1.w * v3.w;
    }
    __syncthreads();
  }
  if (OMODE == 0) {
    size_t ob0 = (size_t)(b * NN + g * GSZ + r0 + rp) * DIMM + h * DH + dx * 4;
    *(float4*)&o[ob0] = make_float4(oa0[0], oa0[1], oa0[2], oa0[3]);
    *(float4*)&o[ob0 + (size_t)16 * DIMM] = make_float4(oa1[0], oa1[1], oa1[2], oa1[3]);
  } else {
    // direct 2-plane bf16 write (same values split_planes(np=2) would produce)
    size_t ob0 = (size_t)(b * NN + g * GSZ + r0 + rp) * 512 + h * 64 + dx * 4;
    ushort4 h0, m0v, h1, m1v;
    unsigned short* h0p = (unsigned short*)&h0;
    unsigned short* m0p = (unsigned short*)&m0v;
    unsigned short* h1p = (unsigned short*)&h1;
    unsigned short* m1p = (unsigned short*)&m1v;
#pragma unroll
    for (int i = 0; i < 4; ++i) {
      unsigned short hh = bf16rne(oa0[i]);
      h0p[i] = hh;
      m0p[i] = bf16rne(oa0[i] - bf16tof(hh));
      unsigned short hh1 = bf16rne(oa1[i]);
      h1p[i] = hh1;
      m1p[i] = bf16rne(oa1[i] - bf16tof(hh1));
    }
    *(ushort4*)&opl[ob0] = h0;
    *(ushort4*)&opl[MK + ob0] = m0v;
    *(ushort4*)&opl[ob0 + 16 * 512] = h1;
    *(ushort4*)&opl[MK + ob0 + 16 * 512] = m1v;
  }
}

// ---------------------------------------------------------------------------
extern "C" void kernel_launch(void* const* d_in, const int* in_sizes, int n_in,
                              void* d_out, int out_size, void* d_ws, size_t ws_size,
                              hipStream_t stream) {
  const float* x      = (const float*)d_in[0];
  const int*   labels = (const int*)d_in[1];
  const float* scores = (const float*)d_in[2];
  const float* Wq     = (const float*)d_in[3];
  const float* Wk     = (const float*)d_in[4];
  const float* Wv     = (const float*)d_in[5];
  const float* Wproj  = (const float*)d_in[6];

  float* out = (float*)d_out;                               // (B, N, DIM)
  float* attn_out = out + (size_t)BB * NN * DIMM;           // (B, ng, H, gs, ws)

  // plane-path layout: qb|kb|vf (fp32) | xpl (3 planes; reused as opl) | weights
  float* qb = (float*)d_ws;
  float* kb = qb + (size_t)MK;
  float* vf = kb + (size_t)MK;
  unsigned short* xpl  = (unsigned short*)(vf + (size_t)MK);
  unsigned short* wqkv = xpl + 3 * (size_t)MK;
  unsigned short* wpp  = wqkv + 9 * (size_t)WK;
  const size_t required = 3 * (size_t)MK * 4 + 3 * (size_t)MK * 2 + 11 * (size_t)WK * 2;

  if (ws_size >= required) {
    split_planes<<<dim3(MK / 1024), 256, 0, stream>>>(x, xpl);
    split_w<<<dim3(4 * WK / 256), 256, 0, stream>>>(Wq, Wk, Wv, Wproj, wqkv, wpp);
    // q,k fp32 via 6-term (bit-identical to round-5 q,k); v fp32 via 3-term
    mfma_gemm<3, 6><<<dim3(4, 128, 2), 256, 0, stream>>>(xpl, wqkv, qb);
    mfma_gemm<2, 3><<<dim3(4, 128, 1), 256, 0, stream>>>(xpl, wqkv + 6 * (size_t)WK, vf);
    // attn: R5-exact selection; o -> 2 bf16 planes into xpl (x planes are dead)
    attn_f32<1><<<dim3(BB * NGRP * HH * 4), 256, 0, stream>>>(
        qb, kb, vf, labels, scores, attn_out, nullptr, xpl);
    mfma_gemm<2, 3><<<dim3(4, 128, 1), 256, 0, stream>>>(xpl, wpp, out);
  } else {
    const size_t SZ = (size_t)BB * NN * DIMM;
    float* q2 = (float*)d_ws;
    float* k2 = q2 + SZ;
    float* v2 = k2 + SZ;
    gemm512<<<dim3(4, 128, 3), 256, 0, stream>>>(x, Wq, Wk, Wv, q2, k2, v2);
    attn_f32<0><<<dim3(BB * NGRP * HH * 4), 256, 0, stream>>>(
        q2, k2, v2, labels, scores, attn_out, q2, nullptr);
    gemm512<<<dim3(4, 128, 1), 256, 0, stream>>>(q2, Wproj, Wproj, Wproj, out, out, out);
  }
}

// Round 9
// 745.218 us; speedup vs baseline: 4.3535x; 1.0882x over previous
//
#include <hip/hip_runtime.h>

#define BB 4
#define NN 4096
#define DIMM 512
#define HH 8
#define DH 64
#define GSZ 128
#define NGRP 32
#define WSZ 256
#define CHUNK 32

#define MK 8388608u     // 16384*512 elements (x / q / k / v / o planes)
#define WK 262144u      // 512*512

typedef short short8 __attribute__((ext_vector_type(8)));
typedef float f32x4 __attribute__((ext_vector_type(4)));

__device__ inline unsigned short bf16rne(float f) {
  unsigned u = __float_as_uint(f);
  unsigned r = u + 0x7FFFu + ((u >> 16) & 1u);
  return (unsigned short)(r >> 16);
}
__device__ inline float bf16tof(unsigned short h) {
  return __uint_as_float(((unsigned)h) << 16);
}

// ---------------------------------------------------------------------------
// split_planes: fp32 -> 3 bf16 planes (hi, mid, lo); exact residual split
// ---------------------------------------------------------------------------
__global__ __launch_bounds__(256) void split_planes(
    const float* __restrict__ X, unsigned short* __restrict__ P)
{
  unsigned idx = (blockIdx.x * 256u + threadIdx.x) * 4u;
  float4 xv = *(const float4*)&X[idx];
  float xs[4] = {xv.x, xv.y, xv.z, xv.w};
  ushort4 hv, mv, lv;
  unsigned short* hp = (unsigned short*)&hv;
  unsigned short* mp = (unsigned short*)&mv;
  unsigned short* lp = (unsigned short*)&lv;
#pragma unroll
  for (int i = 0; i < 4; ++i) {
    unsigned short h = bf16rne(xs[i]);
    float r1 = xs[i] - bf16tof(h);
    unsigned short m = bf16rne(r1);
    float r2 = r1 - bf16tof(m);
    hp[i] = h;
    mp[i] = m;
    lp[i] = bf16rne(r2);
  }
  *(ushort4*)&P[idx] = hv;
  *(ushort4*)&P[MK + idx] = mv;
  *(ushort4*)&P[2u * MK + idx] = lv;
}

// ---------------------------------------------------------------------------
// split_w: weights -> transposed (N x K) bf16 planes.
// ---------------------------------------------------------------------------
__global__ __launch_bounds__(256) void split_w(
    const float* __restrict__ Wq, const float* __restrict__ Wk,
    const float* __restrict__ Wv, const float* __restrict__ Wpj,
    unsigned short* __restrict__ wqkv, unsigned short* __restrict__ wproj)
{
  unsigned e = blockIdx.x * 256u + threadIdx.x;     // over 4 * 2^18
  int mz = e >> 18;
  unsigned rem = e & (WK - 1u);
  unsigned kk = rem >> 9, n = rem & 511u;
  const float* src = (mz == 0) ? Wq : (mz == 1) ? Wk : (mz == 2) ? Wv : Wpj;
  float w = src[kk * 512u + n];
  unsigned short h = bf16rne(w);
  float r1 = w - bf16tof(h);
  unsigned short m = bf16rne(r1);
  float r2 = r1 - bf16tof(m);
  unsigned short l = bf16rne(r2);
  unsigned o = n * 512u + kk;
  if (mz < 3) {
    unsigned short* base = wqkv + (unsigned)mz * 3u * WK;
    base[o] = h;
    base[WK + o] = m;
    base[2u * WK + o] = l;
  } else {
    wproj[o] = h;
    wproj[WK + o] = m;
  }
}

// ---------------------------------------------------------------------------
// mfma_gemm: C[z] = A(16384x512) @ W[z](512x512) via split-bf16 MFMA.
// ---------------------------------------------------------------------------
template <int NP, int NT>
__global__ __launch_bounds__(256) void mfma_gemm(
    const unsigned short* __restrict__ Ap,   // NP planes, plane stride MK
    const unsigned short* __restrict__ Wp,   // [z][NP][n][k], plane stride WK
    float* __restrict__ C)
{
  constexpr int ta[6] = {0, 0, 1, 1, 0, 2};
  constexpr int tw[6] = {0, 1, 0, 1, 2, 0};
  const int z = blockIdx.z;
  const int n0 = blockIdx.x * 128;
  const int m0 = blockIdx.y * 128;
  const int tid = threadIdx.x;
  const int lane = tid & 63, wv = tid >> 6;
  const int wm = (wv >> 1) * 64, wn = (wv & 1) * 64;
  const int lm = lane & 15, lk = (lane >> 4) * 8;

  __shared__ unsigned short As[NP * 128 * 40];   // stride 40 bf16 = 80 B
  __shared__ unsigned short Ws[NP * 128 * 40];

  f32x4 acc[4][4];
#pragma unroll
  for (int i = 0; i < 4; ++i)
#pragma unroll
    for (int j = 0; j < 4; ++j) acc[i][j] = (f32x4){0.f, 0.f, 0.f, 0.f};

  const unsigned short* Wz = Wp + (size_t)z * NP * WK;

  for (int k0 = 0; k0 < 512; k0 += 32) {
#pragma unroll
    for (int i = 0; i < NP * 2; ++i) {
      int idx = i * 256 + tid;
      int p = idx >> 9, rem = idx & 511;
      int r = rem >> 2, cc = rem & 3;
      *(short8*)&As[p * 5120 + r * 40 + cc * 8] =
          *(const short8*)&Ap[(size_t)p * MK + (size_t)(m0 + r) * 512 + k0 + cc * 8];
      *(short8*)&Ws[p * 5120 + r * 40 + cc * 8] =
          *(const short8*)&Wz[(size_t)p * WK + (size_t)(n0 + r) * 512 + k0 + cc * 8];
    }
    __syncthreads();

    short8 a[NP][4];
#pragma unroll
    for (int p = 0; p < NP; ++p)
#pragma unroll
      for (int fm = 0; fm < 4; ++fm)
        a[p][fm] = *(const short8*)&As[p * 5120 + (wm + fm * 16 + lm) * 40 + lk];

#pragma unroll
    for (int fn = 0; fn < 4; ++fn) {
      short8 bf[NP];
#pragma unroll
      for (int p = 0; p < NP; ++p)
        bf[p] = *(const short8*)&Ws[p * 5120 + (wn + fn * 16 + lm) * 40 + lk];
#pragma unroll
      for (int fm = 0; fm < 4; ++fm) {
#pragma unroll
        for (int t = 0; t < NT; ++t)
          acc[fm][fn] = __builtin_amdgcn_mfma_f32_16x16x32_bf16(
              a[ta[t]][fm], bf[tw[t]], acc[fm][fn], 0, 0, 0);
      }
    }
    __syncthreads();
  }

  const int rq = (lane >> 4) * 4;
  float* Cz = C + (size_t)z * 8388608u;
#pragma unroll
  for (int fm = 0; fm < 4; ++fm)
#pragma unroll
    for (int fn = 0; fn < 4; ++fn) {
      int row = m0 + wm + fm * 16 + rq;
      int col = n0 + wn + fn * 16 + lm;
#pragma unroll
      for (int r = 0; r < 4; ++r)
        Cz[(size_t)(row + r) * 512 + col] = acc[fm][fn][r];
    }
}

// ---------------------------------------------------------------------------
// Fallback fp32 GEMM (only if ws too small for planes).
// ---------------------------------------------------------------------------
__global__ __launch_bounds__(256) void gemm512(
    const float* __restrict__ A,
    const float* __restrict__ W0, const float* __restrict__ W1, const float* __restrict__ W2,
    float* __restrict__ C0, float* __restrict__ C1, float* __restrict__ C2)
{
  const int z = blockIdx.z;
  const float* Wm = (z == 0) ? W0 : (z == 1 ? W1 : W2);
  float* Cm = (z == 0) ? C0 : (z == 1 ? C1 : C2);
  const int n0 = blockIdx.x * 128;
  const int m0 = blockIdx.y * 128;
  const int tid = threadIdx.x;
  const int tx = tid & 15, ty = tid >> 4;

  __shared__ float As[32][132];
  __shared__ float Bs[32][132];

  float acc[8][8];
#pragma unroll
  for (int i = 0; i < 8; ++i)
#pragma unroll
    for (int j = 0; j < 8; ++j) acc[i][j] = 0.f;

  for (int k0 = 0; k0 < 512; k0 += 32) {
    {
      const int c4 = tid & 7, r = tid >> 3;
#pragma unroll
      for (int p = 0; p < 128; p += 32) {
        float4 av = *(const float4*)&A[(size_t)(m0 + r + p) * 512 + k0 + c4 * 4];
        As[c4 * 4 + 0][r + p] = av.x;
        As[c4 * 4 + 1][r + p] = av.y;
        As[c4 * 4 + 2][r + p] = av.z;
        As[c4 * 4 + 3][r + p] = av.w;
      }
      const int j4 = tid & 31, rb = tid >> 5;
#pragma unroll
      for (int p = 0; p < 32; p += 8) {
        *(float4*)&Bs[rb + p][j4 * 4] =
            *(const float4*)&Wm[(size_t)(k0 + rb + p) * 512 + n0 + j4 * 4];
      }
    }
    __syncthreads();
#pragma unroll
    for (int kk = 0; kk < 32; ++kk) {
      float4 a0 = *(const float4*)&As[kk][ty * 8];
      float4 a1 = *(const float4*)&As[kk][ty * 8 + 4];
      float4 b0 = *(const float4*)&Bs[kk][tx * 8];
      float4 b1 = *(const float4*)&Bs[kk][tx * 8 + 4];
      float av[8] = {a0.x, a0.y, a0.z, a0.w, a1.x, a1.y, a1.z, a1.w};
      float bv[8] = {b0.x, b0.y, b0.z, b0.w, b1.x, b1.y, b1.z, b1.w};
#pragma unroll
      for (int i = 0; i < 8; ++i)
#pragma unroll
        for (int j = 0; j < 8; ++j) acc[i][j] += av[i] * bv[j];
    }
    __syncthreads();
  }
#pragma unroll
  for (int i = 0; i < 8; ++i) {
    size_t row = (size_t)(m0 + ty * 8 + i);
    float4 o0 = make_float4(acc[i][0], acc[i][1], acc[i][2], acc[i][3]);
    float4 o1 = make_float4(acc[i][4], acc[i][5], acc[i][6], acc[i][7]);
    *(float4*)&Cm[row * 512 + n0 + tx * 8] = o0;
    *(float4*)&Cm[row * 512 + n0 + tx * 8 + 4] = o1;
  }
}

// ---------------------------------------------------------------------------
// focus/keep computation (shared).
// ---------------------------------------------------------------------------
__device__ __forceinline__ void focus_keep(
    const unsigned char* klab, const float* kscr, int* hist8, float* s_var,
    int* s_sk, int* s_ck, int tid, int lane, int wv)
{
  if (tid < GSZ) atomicAdd(&hist8[klab[tid]], 1);
  if (wv == 0) {
    double x0 = (double)kscr[lane], x1 = (double)kscr[lane + 64];
    double s = x0 + x1;
#pragma unroll
    for (int off = 32; off > 0; off >>= 1) s += __shfl_xor(s, off);
    double mean = s * (1.0 / 128.0);
    double d0 = x0 - mean, d1 = x1 - mean;
    double vs = d0 * d0 + d1 * d1;
#pragma unroll
    for (int off = 32; off > 0; off >>= 1) vs += __shfl_xor(vs, off);
    if (lane == 0) *s_var = (float)(vs * (1.0 / 128.0));
  }
  __syncthreads();
  if (tid == 0) {
    int bc = hist8[0];
    for (int l = 1; l < 8; ++l)
      if (hist8[l] > bc) bc = hist8[l];
    float purity = (float)bc * (1.0f / GSZ);
    float focus = 0.5f + 0.25f * purity - 0.25f * (*s_var);
    focus = fminf(fmaxf(focus, 0.25f), 0.75f);
    int keep = (int)ceilf(focus * (float)WSZ);
    keep = min(max(keep, 1), WSZ);
    int ck = keep >> 3, rem = keep & 7;          // round-half-even(keep/8)
    if (rem > 4 || (rem == 4 && (ck & 1))) ck++;
    if (ck < 1) ck = 1;
    int sk = keep - ck;
    if (sk < 1) sk = 1;
    *s_sk = sk;
    *s_ck = ck;
  }
  __syncthreads();
}

// ---------------------------------------------------------------------------
// attn v9: QK fp32-VALU (bit-identical to R8) -> rank (identical compute;
// stores p as in-row bf16 hi/mid overlays + attn_out from regs) -> PV via
// 3-term split-bf16 MFMA (V^T tile staged in LDS, aliasing ktile) -> o as
// 2 bf16 planes for the proj GEMM.
// ---------------------------------------------------------------------------
__global__ __launch_bounds__(256, 3) void attn_v9(
    const float* __restrict__ q, const float* __restrict__ k,
    const float* __restrict__ vf,
    const int* __restrict__ labels, const float* __restrict__ scores,
    float* __restrict__ attn_out, unsigned short* __restrict__ opl)
{
  const int bx = blockIdx.x;
  const int c = bx >> 10;
  const int rblk = bx & 1023;
  const int h = rblk & 7;
  const int g = (rblk >> 3) & 31;
  const int b = rblk >> 8;
  const int r0 = c * CHUNK;
  const int tid = threadIdx.x;
  const int lane = tid & 63, wv = tid >> 6;
  const int lm = lane & 15, lq = lane >> 4;

  // att row = 264 fp32 (1056 B): fp32 logits, later hosts phi[0..263] (528B)
  // + pmid[0..263] (528B) overlays in the SAME row (wave-private, race-free).
  __shared__ float att[CHUNK][264];
  __shared__ __align__(16) unsigned char vbuf[18432];  // ktile f32[64][68] / vtT u16[2][64][72]
  float (*ktile)[68] = (float (*)[68])vbuf;
  unsigned short* vtT = (unsigned short*)vbuf;         // plane stride 4608 shorts
  __shared__ unsigned char klab[WSZ];
  __shared__ float kscr[WSZ];
  __shared__ int hist8[8];
  __shared__ float s_var;
  __shared__ int s_sk, s_ck;

  {
    int j = tid;
    int pos = g * GSZ + j;
    int tok = pos < NN ? pos : (2 * NN - 1 - pos);
    klab[j] = (unsigned char)labels[b * NN + tok];
    kscr[j] = scores[b * NN + tok];
  }
  if (tid < 8) hist8[tid] = 0;
  __syncthreads();
  focus_keep(klab, kscr, hist8, &s_var, &s_sk, &s_ck, tid, lane, wv);
  const int same_keep = s_sk, cross_keep = s_ck;

  const int rp = tid >> 4, jx = tid & 15;
  const int srow = tid >> 4, sd4 = (tid & 15) * 4;
  const float* q0p = q + (size_t)(b * NN + g * GSZ + r0 + rp) * DIMM + h * DH;
  const float* q1p = q0p + (size_t)16 * DIMM;

  // ---- QK^T: fp32 VALU, arithmetic identical to R8 (selection-critical) ----
  for (int jt = 0; jt < 4; ++jt) {
#pragma unroll
    for (int p = 0; p < 64; p += 16) {
      int j = jt * 64 + srow + p;
      int pos = g * GSZ + j;
      int tok = pos < NN ? pos : (2 * NN - 1 - pos);
      *(float4*)&ktile[srow + p][sd4] =
          *(const float4*)&k[(size_t)(b * NN + tok) * DIMM + h * DH + sd4];
    }
    __syncthreads();
    float acc0[4] = {0.f, 0.f, 0.f, 0.f}, acc1[4] = {0.f, 0.f, 0.f, 0.f};
#pragma unroll
    for (int dd = 0; dd < DH; dd += 4) {
      float4 q0 = *(const float4*)(q0p + dd);
      float4 q1 = *(const float4*)(q1p + dd);
#pragma unroll
      for (int jj = 0; jj < 4; ++jj) {
        float4 kv = *(const float4*)&ktile[jx + 16 * jj][dd];
        acc0[jj] += q0.x * kv.x + q0.y * kv.y + q0.z * kv.z + q0.w * kv.w;
        acc1[jj] += q1.x * kv.x + q1.y * kv.y + q1.z * kv.z + q1.w * kv.w;
      }
    }
#pragma unroll
    for (int jj = 0; jj < 4; ++jj) {
      att[rp][jt * 64 + jx + 16 * jj] = acc0[jj] * 0.125f;
      att[rp + 16][jt * 64 + jx + 16 * jj] = acc1[jj] * 0.125f;
    }
    __syncthreads();
  }

  // ---- rank: identical compute; new store (overlays + attn_out from regs) --
  {
    int kl0[4];
    float ks0[4];
#pragma unroll
    for (int m = 0; m < 4; ++m) {
      kl0[m] = klab[lane + 64 * m];
      ks0[m] = kscr[lane + 64 * m];
    }
    for (int sp = 0; sp < 4; ++sp) {
      const int rA = wv * 8 + 2 * sp, rB = rA + 1;
      const int qLA = klab[r0 + rA], qLB = klab[r0 + rB];
      const float qSA = kscr[r0 + rA], qSB = kscr[r0 + rB];
      float aA[4], aB[4];
      float mxA = -INFINITY, mxB = -INFINITY;
#pragma unroll
      for (int m = 0; m < 4; ++m) {
        aA[m] = att[rA][lane + 64 * m];
        aB[m] = att[rB][lane + 64 * m];
        mxA = fmaxf(mxA, aA[m]);
        mxB = fmaxf(mxB, aB[m]);
      }
#pragma unroll
      for (int off = 32; off > 0; off >>= 1) {
        mxA = fmaxf(mxA, __shfl_xor(mxA, off));
        mxB = fmaxf(mxB, __shfl_xor(mxB, off));
      }
      unsigned fsA[4], fcA[4], fsB[4], fcB[4];
      bool cdA[4], cdB[4];
#pragma unroll
      for (int m = 0; m < 4; ++m) {
        aA[m] = expf(aA[m] - mxA);
        aB[m] = expf(aB[m] - mxB);
        cdA[m] = (kl0[m] == qLA);
        cdB[m] = (kl0[m] == qLB);
        fsA[m] = cdA[m] ? __float_as_uint(aA[m]) : 0u;
        fsB[m] = cdB[m] ? __float_as_uint(aB[m]) : 0u;
        fcA[m] = __float_as_uint(aA[m] * (qSA * ks0[m]));
        fcB[m] = __float_as_uint(aB[m] * (qSB * ks0[m]));
      }
      unsigned tsA = 0, tcA = 0, tsB = 0, tcB = 0;
      for (int bit = 29; bit >= 0; --bit) {
        unsigned csA = tsA | (1u << bit), ccA = tcA | (1u << bit);
        unsigned csB = tsB | (1u << bit), ccB = tcB | (1u << bit);
        int nsA = 0, ncA = 0, nsB = 0, ncB = 0;
#pragma unroll
        for (int m = 0; m < 4; ++m) {
          nsA += __popcll(__ballot(fsA[m] >= csA));
          ncA += __popcll(__ballot(fcA[m] >= ccA));
          nsB += __popcll(__ballot(fsB[m] >= csB));
          ncB += __popcll(__ballot(fcB[m] >= ccB));
        }
        if (nsA >= same_keep) tsA = csA;
        if (ncA >= cross_keep) tcA = ccA;
        if (nsB >= same_keep) tsB = csB;
        if (ncB >= cross_keep) tcB = ccB;
      }
#pragma unroll
      for (int rsel = 0; rsel < 2; ++rsel) {
        const int rr = rsel ? rB : rA;
        const unsigned ts = rsel ? tsB : tsA, tc = rsel ? tcB : tcA;
        unsigned* fs = rsel ? fsB : fsA;
        unsigned* fc = rsel ? fcB : fcA;
        float* a = rsel ? aB : aA;
        bool* cand = rsel ? cdB : cdA;
        unsigned long long beqs[4], beqc[4];
        int gts = 0, gtc = 0;
#pragma unroll
        for (int m = 0; m < 4; ++m) {
          gts += __popcll(__ballot(fs[m] > ts));
          gtc += __popcll(__ballot(fc[m] > tc));
          beqs[m] = __ballot(fs[m] == ts);
          beqc[m] = __ballot(fc[m] == tc);
        }
        const int rs = same_keep - gts, rc = cross_keep - gtc;
        float pv[4];
        float S = 0.f;
        int pres = 0, prec = 0;
#pragma unroll
        for (int m = 0; m < 4; ++m) {
          int mbs = __builtin_amdgcn_mbcnt_hi((unsigned)(beqs[m] >> 32),
                     __builtin_amdgcn_mbcnt_lo((unsigned)beqs[m], 0));
          int mbc = __builtin_amdgcn_mbcnt_hi((unsigned)(beqc[m] >> 32),
                     __builtin_amdgcn_mbcnt_lo((unsigned)beqc[m], 0));
          bool keep_s = cand[m] && ((fs[m] > ts) || ((fs[m] == ts) && (pres + mbs < rs)));
          bool keep_c = (!cand[m]) && ((fc[m] > tc) || ((fc[m] == tc) && (prec + mbc < rc)));
          pv[m] = (keep_s || keep_c) ? a[m] : 0.f;
          S += pv[m];
          pres += __popcll(beqs[m]);
          prec += __popcll(beqc[m]);
        }
#pragma unroll
        for (int off = 32; off > 0; off >>= 1) S += __shfl_xor(S, off);
        const float inv = 1.0f / S;
        size_t gb = ((((size_t)b * NGRP + g) * HH + h) * GSZ + (r0 + rr)) * WSZ + lane;
        unsigned short* prow = (unsigned short*)&att[rr][0];
#pragma unroll
        for (int m = 0; m < 4; ++m) {
          float p = pv[m] * inv;
          attn_out[gb + 64 * m] = p;
          unsigned short hh = bf16rne(p);
          prow[lane + 64 * m] = hh;                          // phi
          prow[264 + lane + 64 * m] = bf16rne(p - bf16tof(hh)); // pmid
        }
      }
    }
  }

  // ---- PV via MFMA: D(32x64) = P(32x256) @ V(256x64), 3-term split ----
  f32x4 acc2[2] = {(f32x4){0.f, 0.f, 0.f, 0.f}, (f32x4){0.f, 0.f, 0.f, 0.f}};
  for (int jt = 0; jt < 4; ++jt) {
    __syncthreads();   // overlays done (jt=0) / prior MFMA reads done (jt>0)
    // stage V^T tile: vtT[pl][d][j], 64 j of this jt; pair-packed b32 writes
    {
      const int dx_ = tid & 15, jh = tid >> 4;      // jh 0..15
#pragma unroll
      for (int ps = 0; ps < 2; ++ps) {
        int jl0 = ps * 32 + 2 * jh;
        float4 v0, v1;
#pragma unroll
        for (int qq = 0; qq < 2; ++qq) {
          int pos = g * GSZ + jt * 64 + jl0 + qq;
          int tok = pos < NN ? pos : (2 * NN - 1 - pos);
          float4 vv = *(const float4*)&vf[(size_t)(b * NN + tok) * DIMM + h * DH + dx_ * 4];
          if (qq == 0) v0 = vv; else v1 = vv;
        }
        const float* a0 = (const float*)&v0;
        const float* a1 = (const float*)&v1;
#pragma unroll
        for (int i = 0; i < 4; ++i) {
          int d = dx_ * 4 + i;
          unsigned short h0 = bf16rne(a0[i]);
          unsigned short h1 = bf16rne(a1[i]);
          unsigned short m0 = bf16rne(a0[i] - bf16tof(h0));
          unsigned short m1 = bf16rne(a1[i] - bf16tof(h1));
          *(unsigned*)&vtT[0 * 4608 + d * 72 + jl0] = (unsigned)h0 | ((unsigned)h1 << 16);
          *(unsigned*)&vtT[1 * 4608 + d * 72 + jl0] = (unsigned)m0 | ((unsigned)m1 << 16);
        }
      }
    }
    __syncthreads();
#pragma unroll
    for (int kt = 0; kt < 2; ++kt) {
      const int koff = jt * 64 + kt * 32 + lq * 8;
      short8 ahi[2], ami[2];
#pragma unroll
      for (int mt = 0; mt < 2; ++mt) {
        const unsigned short* arow = (const unsigned short*)&att[mt * 16 + lm][0];
        ahi[mt] = *(const short8*)&arow[koff];
        ami[mt] = *(const short8*)&arow[264 + koff];
      }
      const int vo = (wv * 16 + lm) * 72 + kt * 32 + lq * 8;
      short8 bhi = *(const short8*)&vtT[vo];
      short8 bmi = *(const short8*)&vtT[4608 + vo];
#pragma unroll
      for (int mt = 0; mt < 2; ++mt) {
        acc2[mt] = __builtin_amdgcn_mfma_f32_16x16x32_bf16(ahi[mt], bhi, acc2[mt], 0, 0, 0);
        acc2[mt] = __builtin_amdgcn_mfma_f32_16x16x32_bf16(ahi[mt], bmi, acc2[mt], 0, 0, 0);
        acc2[mt] = __builtin_amdgcn_mfma_f32_16x16x32_bf16(ami[mt], bhi, acc2[mt], 0, 0, 0);
      }
    }
  }

  // ---- o epilogue: C/D col=lane&15 (d), row=lq*4+r (+mt*16); 2 bf16 planes --
  {
    size_t rowbase = (size_t)(b * NN + g * GSZ + r0);
#pragma unroll
    for (int mt = 0; mt < 2; ++mt)
#pragma unroll
      for (int r = 0; r < 4; ++r) {
        int row = mt * 16 + lq * 4 + r;
        float val = acc2[mt][r];
        unsigned short hh = bf16rne(val);
        size_t oaddr = (rowbase + row) * 512 + h * 64 + wv * 16 + lm;
        opl[oaddr] = hh;
        opl[MK + oaddr] = bf16rne(val - bf16tof(hh));
      }
  }
}

// ---------------------------------------------------------------------------
// Fallback attn (fp32 q/k/v in, fp32 o out aliasing q) — small-ws path only.
// ---------------------------------------------------------------------------
__global__ __launch_bounds__(256, 3) void attn_f32(
    const float* q, const float* __restrict__ k, const float* __restrict__ v,
    const int* __restrict__ labels, const float* __restrict__ scores,
    float* __restrict__ attn_out, float* o)
{
  const int bx = blockIdx.x;
  const int c = bx >> 10;
  const int rblk = bx & 1023;
  const int h = rblk & 7;
  const int g = (rblk >> 3) & 31;
  const int b = rblk >> 8;
  const int r0 = c * CHUNK;
  const int tid = threadIdx.x;
  const int lane = tid & 63, wv = tid >> 6;

  __shared__ float att[CHUNK][WSZ + 4];
  __shared__ float ktile[64][DH + 4];
  __shared__ unsigned char klab[WSZ];
  __shared__ float kscr[WSZ];
  __shared__ int hist8[8];
  __shared__ float s_var;
  __shared__ int s_sk, s_ck;

  {
    int j = tid;
    int pos = g * GSZ + j;
    int tok = pos < NN ? pos : (2 * NN - 1 - pos);
    klab[j] = (unsigned char)labels[b * NN + tok];
    kscr[j] = scores[b * NN + tok];
  }
  if (tid < 8) hist8[tid] = 0;
  __syncthreads();
  focus_keep(klab, kscr, hist8, &s_var, &s_sk, &s_ck, tid, lane, wv);
  const int same_keep = s_sk, cross_keep = s_ck;

  const int rp = tid >> 4, jx = tid & 15;
  const int srow = tid >> 4, sd4 = (tid & 15) * 4;
  const float* q0p = q + (size_t)(b * NN + g * GSZ + r0 + rp) * DIMM + h * DH;
  const float* q1p = q0p + (size_t)16 * DIMM;

  for (int jt = 0; jt < 4; ++jt) {
#pragma unroll
    for (int p = 0; p < 64; p += 16) {
      int j = jt * 64 + srow + p;
      int pos = g * GSZ + j;
      int tok = pos < NN ? pos : (2 * NN - 1 - pos);
      *(float4*)&ktile[srow + p][sd4] =
          *(const float4*)&k[(size_t)(b * NN + tok) * DIMM + h * DH + sd4];
    }
    __syncthreads();
    float acc0[4] = {0.f, 0.f, 0.f, 0.f}, acc1[4] = {0.f, 0.f, 0.f, 0.f};
#pragma unroll
    for (int dd = 0; dd < DH; dd += 4) {
      float4 q0 = *(const float4*)(q0p + dd);
      float4 q1 = *(const float4*)(q1p + dd);
#pragma unroll
      for (int jj = 0; jj < 4; ++jj) {
        float4 kv = *(const float4*)&ktile[jx + 16 * jj][dd];
        acc0[jj] += q0.x * kv.x + q0.y * kv.y + q0.z * kv.z + q0.w * kv.w;
        acc1[jj] += q1.x * kv.x + q1.y * kv.y + q1.z * kv.z + q1.w * kv.w;
      }
    }
#pragma unroll
    for (int jj = 0; jj < 4; ++jj) {
      att[rp][jt * 64 + jx + 16 * jj] = acc0[jj] * 0.125f;
      att[rp + 16][jt * 64 + jx + 16 * jj] = acc1[jj] * 0.125f;
    }
    __syncthreads();
  }

  {
    int kl0[4];
    float ks0[4];
#pragma unroll
    for (int m = 0; m < 4; ++m) {
      kl0[m] = klab[lane + 64 * m];
      ks0[m] = kscr[lane + 64 * m];
    }
    for (int sp = 0; sp < 4; ++sp) {
      const int rA = wv * 8 + 2 * sp, rB = rA + 1;
      const int qLA = klab[r0 + rA], qLB = klab[r0 + rB];
      const float qSA = kscr[r0 + rA], qSB = kscr[r0 + rB];
      float aA[4], aB[4];
      float mxA = -INFINITY, mxB = -INFINITY;
#pragma unroll
      for (int m = 0; m < 4; ++m) {
        aA[m] = att[rA][lane + 64 * m];
        aB[m] = att[rB][lane + 64 * m];
        mxA = fmaxf(mxA, aA[m]);
        mxB = fmaxf(mxB, aB[m]);
      }
#pragma unroll
      for (int off = 32; off > 0; off >>= 1) {
        mxA = fmaxf(mxA, __shfl_xor(mxA, off));
        mxB = fmaxf(mxB, __shfl_xor(mxB, off));
      }
      unsigned fsA[4], fcA[4], fsB[4], fcB[4];
      bool cdA[4], cdB[4];
#pragma unroll
      for (int m = 0; m < 4; ++m) {
        aA[m] = expf(aA[m] - mxA);
        aB[m] = expf(aB[m] - mxB);
        cdA[m] = (kl0[m] == qLA);
        cdB[m] = (kl0[m] == qLB);
        fsA[m] = cdA[m] ? __float_as_uint(aA[m]) : 0u;
        fsB[m] = cdB[m] ? __float_as_uint(aB[m]) : 0u;
        fcA[m] = __float_as_uint(aA[m] * (qSA * ks0[m]));
        fcB[m] = __float_as_uint(aB[m] * (qSB * ks0[m]));
      }
      unsigned tsA = 0, tcA = 0, tsB = 0, tcB = 0;
      for (int bit = 29; bit >= 0; --bit) {
        unsigned csA = tsA | (1u << bit), ccA = tcA | (1u << bit);
        unsigned csB = tsB | (1u << bit), ccB = tcB | (1u << bit);
        int nsA = 0, ncA = 0, nsB = 0, ncB = 0;
#pragma unroll
        for (int m = 0; m < 4; ++m) {
          nsA += __popcll(__ballot(fsA[m] >= csA));
          ncA += __popcll(__ballot(fcA[m] >= ccA));
          nsB += __popcll(__ballot(fsB[m] >= csB));
          ncB += __popcll(__ballot(fcB[m] >= ccB));
        }
        if (nsA >= same_keep) tsA = csA;
        if (ncA >= cross_keep) tcA = ccA;
        if (nsB >= same_keep) tsB = csB;
        if (ncB >= cross_keep) tcB = ccB;
      }
#pragma unroll
      for (int rsel = 0; rsel < 2; ++rsel) {
        const int rr = rsel ? rB : rA;
        const unsigned ts = rsel ? tsB : tsA, tc = rsel ? tcB : tcA;
        unsigned* fs = rsel ? fsB : fsA;
        unsigned* fc = rsel ? fcB : fcA;
        float* a = rsel ? aB : aA;
        bool* cand = rsel ? cdB : cdA;
        unsigned long long beqs[4], beqc[4];
        int gts = 0, gtc = 0;
#pragma unroll
        for (int m = 0; m < 4; ++m) {
          gts += __popcll(__ballot(fs[m] > ts));
          gtc += __popcll(__ballot(fc[m] > tc));
          beqs[m] = __ballot(fs[m] == ts);
          beqc[m] = __ballot(fc[m] == tc);
        }
        const int rs = same_keep - gts, rc = cross_keep - gtc;
        float pv[4];
        float S = 0.f;
        int pres = 0, prec = 0;
#pragma unroll
        for (int m = 0; m < 4; ++m) {
          int mbs = __builtin_amdgcn_mbcnt_hi((unsigned)(beqs[m] >> 32),
                     __builtin_amdgcn_mbcnt_lo((unsigned)beqs[m], 0));
          int mbc = __builtin_amdgcn_mbcnt_hi((unsigned)(beqc[m] >> 32),
                     __builtin_amdgcn_mbcnt_lo((unsigned)beqc[m], 0));
          bool keep_s = cand[m] && ((fs[m] > ts) || ((fs[m] == ts) && (pres + mbs < rs)));
          bool keep_c = (!cand[m]) && ((fc[m] > tc) || ((fc[m] == tc) && (prec + mbc < rc)));
          pv[m] = (keep_s || keep_c) ? a[m] : 0.f;
          S += pv[m];
          pres += __popcll(beqs[m]);
          prec += __popcll(beqc[m]);
        }
#pragma unroll
        for (int off = 32; off > 0; off >>= 1) S += __shfl_xor(S, off);
        const float inv = 1.0f / S;
        size_t gb = ((((size_t)b * NGRP + g) * HH + h) * GSZ + (r0 + rr)) * WSZ + lane;
#pragma unroll
        for (int m = 0; m < 4; ++m) {
          float p = pv[m] * inv;
          att[rr][lane + 64 * m] = p;
          attn_out[gb + 64 * m] = p;
        }
      }
    }
  }
  __syncthreads();

  const int dx = jx;
  float oa0[4] = {0.f, 0.f, 0.f, 0.f}, oa1[4] = {0.f, 0.f, 0.f, 0.f};
  for (int jt = 0; jt < 4; ++jt) {
#pragma unroll
    for (int p = 0; p < 64; p += 16) {
      int j = jt * 64 + srow + p;
      int pos = g * GSZ + j;
      int tok = pos < NN ? pos : (2 * NN - 1 - pos);
      *(float4*)&ktile[srow + p][sd4] =
          *(const float4*)&v[(size_t)(b * NN + tok) * DIMM + h * DH + sd4];
    }
    __syncthreads();
#pragma unroll 4
    for (int jg = 0; jg < 16; ++jg) {
      float4 p0 = *(const float4*)&att[rp][jt * 64 + jg * 4];
      float4 p1 = *(const float4*)&att[rp + 16][jt * 64 + jg * 4];
      float4 v0 = *(const float4*)&ktile[jg * 4 + 0][dx * 4];
      float4 v1 = *(const float4*)&ktile[jg * 4 + 1][dx * 4];
      float4 v2 = *(const float4*)&ktile[jg * 4 + 2][dx * 4];
      float4 v3 = *(const float4*)&ktile[jg * 4 + 3][dx * 4];
      oa0[0] += p0.x * v0.x + p0.y * v1.x + p0.z * v2.x + p0.w * v3.x;
      oa0[1] += p0.x * v0.y + p0.y * v1.y + p0.z * v2.y + p0.w * v3.y;
      oa0[2] += p0.x * v0.z + p0.y * v1.z + p0.z * v2.z + p0.w * v3.z;
      oa0[3] += p0.x * v0.w + p0.y * v1.w + p0.z * v2.w + p0.w * v3.w;
      oa1[0] += p1.x * v0.x + p1.y * v1.x + p1.z * v2.x + p1.w * v3.x;
      oa1[1] += p1.x * v0.y + p1.y * v1.y + p1.z * v2.y + p1.w * v3.y;
      oa1[2] += p1.x * v0.z + p1.y * v1.z + p1.z * v2.z + p1.w * v3.z;
      oa1[3] += p1.x * v0.w + p1.y * v1.w + p1.z * v2.w + p1.w * v3.w;
    }
    __syncthreads();
  }
  {
    size_t ob0 = (size_t)(b * NN + g * GSZ + r0 + rp) * DIMM + h * DH + dx * 4;
    *(float4*)&o[ob0] = make_float4(oa0[0], oa0[1], oa0[2], oa0[3]);
    *(float4*)&o[ob0 + (size_t)16 * DIMM] = make_float4(oa1[0], oa1[1], oa1[2], oa1[3]);
  }
}

// ---------------------------------------------------------------------------
extern "C" void kernel_launch(void* const* d_in, const int* in_sizes, int n_in,
                              void* d_out, int out_size, void* d_ws, size_t ws_size,
                              hipStream_t stream) {
  const float* x      = (const float*)d_in[0];
  const int*   labels = (const int*)d_in[1];
  const float* scores = (const float*)d_in[2];
  const float* Wq     = (const float*)d_in[3];
  const float* Wk     = (const float*)d_in[4];
  const float* Wv     = (const float*)d_in[5];
  const float* Wproj  = (const float*)d_in[6];

  float* out = (float*)d_out;                               // (B, N, DIM)
  float* attn_out = out + (size_t)BB * NN * DIMM;           // (B, ng, H, gs, ws)

  // layout: qb|kb|vf (fp32) | xpl (3 planes; reused as opl) | weights
  float* qb = (float*)d_ws;
  float* kb = qb + (size_t)MK;
  float* vf = kb + (size_t)MK;
  unsigned short* xpl  = (unsigned short*)(vf + (size_t)MK);
  unsigned short* wqkv = xpl + 3 * (size_t)MK;
  unsigned short* wpp  = wqkv + 9 * (size_t)WK;
  const size_t required = 3 * (size_t)MK * 4 + 3 * (size_t)MK * 2 + 11 * (size_t)WK * 2;

  if (ws_size >= required) {
    split_planes<<<dim3(MK / 1024), 256, 0, stream>>>(x, xpl);
    split_w<<<dim3(4 * WK / 256), 256, 0, stream>>>(Wq, Wk, Wv, Wproj, wqkv, wpp);
    // q,k fp32 via 6-term (bit-identical to R5/R8 selection inputs); v 3-term
    mfma_gemm<3, 6><<<dim3(4, 128, 2), 256, 0, stream>>>(xpl, wqkv, qb);
    mfma_gemm<2, 3><<<dim3(4, 128, 1), 256, 0, stream>>>(xpl, wqkv + 6 * (size_t)WK, vf);
    attn_v9<<<dim3(BB * NGRP * HH * 4), 256, 0, stream>>>(
        qb, kb, vf, labels, scores, attn_out, xpl);
    mfma_gemm<2, 3><<<dim3(4, 128, 1), 256, 0, stream>>>(xpl, wpp, out);
  } else {
    const size_t SZ = (size_t)BB * NN * DIMM;
    float* q2 = (float*)d_ws;
    float* k2 = q2 + SZ;
    float* v2 = k2 + SZ;
    gemm512<<<dim3(4, 128, 3), 256, 0, stream>>>(x, Wq, Wk, Wv, q2, k2, v2);
    attn_f32<<<dim3(BB * NGRP * HH * 4), 256, 0, stream>>>(
        q2, k2, v2, labels, scores, attn_out, q2);
    gemm512<<<dim3(4, 128, 1), 256, 0, stream>>>(q2, Wproj, Wproj, Wproj, out, out, out);
  }
}